// Round 13
// baseline (457.224 us; speedup 1.0000x reference)
//
#include <hip/hip_runtime.h>
#include <math.h>

// ---- model sizes ----
#define BB 16
#define TT 128
#define CC 64
#define FF 128
// H=4, FO=16, H*FO=64, HID=32

static constexpr float INV_TEMP = 1.0f / 1.5f;

// ---- workspace offsets (in floats) ----
static constexpr size_t OFF_WRT   = 8192;       // 16384  WRT[k][g]: g<64 gat_W^T, g>=64 gat_res_W^T
static constexpr size_t OFF_TAWT  = 24576;      //  4096  taWT[v][u]
static constexpr size_t OFF_AN    = 28672;      // 65536  An[b][i][j] row-major
static constexpr size_t OFF_A     = 94208;      // 65536  A[b][c][d]
static constexpr size_t OFF_G     = 1208320;    // 8388608 GAT output [b][t][c][64]
static constexpr size_t OFF_H     = 9596928;    // 8388608 BiLSTM out [n][tau][64]
static constexpr size_t OFF_HP    = 17985536;   // 65536  pooled [n][64]
static constexpr size_t OFF_WIHT  = 18051072;   // 16384  WihT[dir][64k][128g]
static constexpr size_t OFF_ZX    = 18067456;   // 33554432 zx[dir][n*128+t][128]
// aliases inside ZX region (all dead before k_zx runs):
static constexpr size_t OFF_WHS   = OFF_ZX + 16777216;  //  8388608: Wh [bt][64][64]
static constexpr size_t OFF_RS    = OFF_ZX + 25165824;  //  8388608: res+bias [bt][64][64]
// APART (corr partials) aliases the WHS region: alive only corr -> reduceA.
static constexpr size_t OFF_APART = OFF_WHS;            //  4194304 floats used

// ---------------------------------------------------------------- prep: weight transposes
__global__ __launch_bounds__(256) void k_prep(const float* __restrict__ gat_W,
                                              const float* __restrict__ gat_rW,
                                              const float* __restrict__ ta_W,
                                              const float* __restrict__ Wihf,
                                              const float* __restrict__ Wihb,
                                              float* __restrict__ ws) {
    int i = blockIdx.x * 256 + threadIdx.x;  // < 36864, grid 144
    if (i < 16384) {
        // WRT[k][g]: combined [128k][128g] (cols 0-63 = gat_W^T, 64-127 = gat_res_W^T)
        int k = i >> 7, g = i & 127;
        ws[OFF_WRT + i] = (g < 64) ? gat_W[g * 128 + k] : gat_rW[(g - 64) * 128 + k];
    } else if (i < 20480) {
        int j = i - 16384; int v = j >> 6, u = j & 63;
        ws[OFF_TAWT + j] = ta_W[u * 64 + v];
    } else if (i < 36864) {
        int j = i - 20480;  // WihT[dir][k][g] = Wih_dir[g][k]
        int dir = j >> 13, rem = j & 8191, k = rem >> 7, gg = rem & 127;
        const float* W = dir ? Wihb : Wihf;
        ws[OFF_WIHT + j] = W[gg * 64 + k];
    }
}

__device__ __forceinline__ float4 sigmul4(const float4 xv, const float4 wv) {
    float4 o;
    o.x = xv.x / (1.f + __expf(-wv.x));
    o.y = xv.y / (1.f + __expf(-wv.y));
    o.z = xv.z / (1.f + __expf(-wv.z));
    o.w = xv.w / (1.f + __expf(-wv.w));
    return o;
}

// ---------------------------------------------------------------- corr partial grams
__global__ __launch_bounds__(256) void k_corr(const float* __restrict__ x,
                                              const float* __restrict__ spec_w,
                                              float* __restrict__ ws) {
    __shared__ __align__(16) float tile[64 * 132];
    __shared__ float rn[64];
    const int ch = blockIdx.x, b = blockIdx.y, tid = threadIdx.x;
    const int lane = tid & 63, wave = tid >> 6;
    const int c0 = wave * 16 + ((lane >> 4) << 2);
    const int d0 = (lane & 15) << 2;
    const float4* __restrict__ sg4 = (const float4*)spec_w;
    float acc[4][4];
#pragma unroll
    for (int a = 0; a < 4; ++a)
#pragma unroll
        for (int e = 0; e < 4; ++e) acc[a][e] = 0.f;

    for (int t8 = 0; t8 < 2; ++t8) {
        const int t = ch * 2 + t8;
        __syncthreads();
        const float4* __restrict__ xp4 = (const float4*)(x + ((size_t)(b * TT + t)) * CC * FF);
        for (int i4 = tid; i4 < 2048; i4 += 256) {
            const int row = i4 >> 5, col4 = i4 & 31;
            *(float4*)&tile[row * 132 + col4 * 4] = sigmul4(xp4[i4], sg4[i4]);
        }
        __syncthreads();
        {   // row norms: 4 threads per row
            const int row = tid >> 2, part = tid & 3;
            const float4* tr = (const float4*)(tile + row * 132 + part * 32);
            float s = 0.f;
#pragma unroll
            for (int q = 0; q < 8; ++q) {
                const float4 v = tr[q];
                s += v.x * v.x + v.y * v.y + v.z * v.z + v.w * v.w;
            }
            s += __shfl_xor(s, 1); s += __shfl_xor(s, 2);
            if (part == 0) rn[row] = 1.f / (sqrtf(s) + 1e-8f);
        }
        __syncthreads();
        float dot[4][4];
#pragma unroll
        for (int a = 0; a < 4; ++a)
#pragma unroll
            for (int e = 0; e < 4; ++e) dot[a][e] = 0.f;
        for (int f4 = 0; f4 < 32; ++f4) {
            float4 xc4[4], xd4[4];
#pragma unroll
            for (int a = 0; a < 4; ++a) xc4[a] = *(const float4*)&tile[(c0 + a) * 132 + f4 * 4];
#pragma unroll
            for (int e = 0; e < 4; ++e) xd4[e] = *(const float4*)&tile[(d0 + e) * 132 + f4 * 4];
#pragma unroll
            for (int a = 0; a < 4; ++a)
#pragma unroll
                for (int e = 0; e < 4; ++e)
                    dot[a][e] += xc4[a].x * xd4[e].x + xc4[a].y * xd4[e].y +
                                 xc4[a].z * xd4[e].z + xc4[a].w * xd4[e].w;
        }
#pragma unroll
        for (int a = 0; a < 4; ++a) {
            const float ra = rn[c0 + a];
#pragma unroll
            for (int e = 0; e < 4; ++e) acc[a][e] += ra * rn[d0 + e] * dot[a][e];
        }
    }
    float* __restrict__ Ap = ws + OFF_APART + ((size_t)(b * 64 + ch)) * 4096;
#pragma unroll
    for (int a = 0; a < 4; ++a)
#pragma unroll
        for (int e = 0; e < 4; ++e) Ap[(c0 + a) * 64 + d0 + e] = acc[a][e];
}

// ---------------------------------------------------------------- reduce A (deterministic)
__global__ __launch_bounds__(256) void k_reduceA(float* __restrict__ ws) {
    int i = blockIdx.x * 256 + threadIdx.x;  // < 65536
    int b = i >> 12, e = i & 4095;
    const float* Ap = ws + OFF_APART + (size_t)b * 64 * 4096;
    float s = 0.f;
#pragma unroll 8
    for (int ch = 0; ch < 64; ++ch) s += Ap[ch * 4096 + e];
    ws[OFF_A + i] = s * (1.f / 128.f);
}

// ---------------------------------------------------------------- top-k sparsify -> An[i][j]
__global__ __launch_bounds__(64) void k_sparsify(float* __restrict__ ws) {
    __shared__ float As[64 * 65];
    __shared__ unsigned char kp[64 * 64];
    const int b = blockIdx.x, tid = threadIdx.x;  // 64 threads
    const float* Ag = ws + OFF_A + (size_t)b * 4096;
    for (int m = 0; m < 64; ++m) As[m * 65 + tid] = Ag[m * 64 + tid];
    __syncthreads();
    const int c = tid;
    int s0 = -1, s1 = -1, s2 = -1;
    for (int p = 0; p < 3; ++p) {
        float best = -1e30f; int bi = -1;
        for (int d = 0; d < 64; ++d) {
            if (d == s0 || d == s1) continue;
            float v = As[c * 65 + d];
            if (v > best) { best = v; bi = d; }
        }
        if (p == 0) s0 = bi; else if (p == 1) s1 = bi; else s2 = bi;
    }
    for (int d = 0; d < 64; ++d) {
        float v = As[c * 65 + d];
        kp[c * 64 + d] = (unsigned char)(((d == s0) | (d == s1) | (d == s2)) &&
                                         (v > 0.3f) && (d != c));
    }
    __syncthreads();
    float rs = 0.f;
    for (int d = 0; d < 64; ++d) {
        bool k2 = kp[c * 64 + d] || kp[d * 64 + c];
        rs += k2 ? As[c * 65 + d] : 0.f;
    }
    const float inv = 1.f / (rs + 1e-8f);
    float* An = ws + OFF_AN + (size_t)b * 4096;
    for (int d = 0; d < 64; ++d) {
        bool k2 = kp[c * 64 + d] || kp[d * 64 + c];
        An[c * 64 + d] = k2 ? As[c * 65 + d] * inv : 0.f;  // row-major [i][j]
    }
}

// ---------------------------------------------------------------- batched GEMM: [Wh|res] = xw @ WRT
// R13: reverted to R11's 8-row x 4-col tile (R12's 4x8 retile doubled global
// weight-load instructions and regressed 420->432). Combined WRT kept.
__global__ __launch_bounds__(256) void k_wh(const float* __restrict__ x,
                                            const float* __restrict__ spec_w,
                                            const float* __restrict__ wrt,
                                            float* __restrict__ whs,
                                            float* __restrict__ rs,
                                            const float* __restrict__ res_b) {
    __shared__ __align__(16) float tile[64 * 132];
    const int bt = blockIdx.x, tid = threadIdx.x;
    const float4* __restrict__ xp4 = (const float4*)(x + (size_t)bt * 8192);
    const float4* __restrict__ sg4 = (const float4*)spec_w;
    for (int i4 = tid; i4 < 2048; i4 += 256) {
        const int row = i4 >> 5, col4 = i4 & 31;
        *(float4*)&tile[row * 132 + col4 * 4] = sigmul4(xp4[i4], sg4[i4]);
    }
    __syncthreads();
    const int tx = tid & 31, ty = tid >> 5;
    const int mat = tx >> 4, cx = tx & 15;
    const int r0 = ty * 8, c0 = cx * 4;
    const float* __restrict__ wbase = wrt + (mat ? 64 : 0);
    float acc[8][4];
#pragma unroll
    for (int i = 0; i < 8; ++i)
#pragma unroll
        for (int j = 0; j < 4; ++j) acc[i][j] = 0.f;
    for (int k4 = 0; k4 < 32; ++k4) {
        float xs[8][4];
#pragma unroll
        for (int i = 0; i < 8; ++i) {
            const float4 v = *(const float4*)&tile[(r0 + i) * 132 + k4 * 4];
            xs[i][0] = v.x; xs[i][1] = v.y; xs[i][2] = v.z; xs[i][3] = v.w;
        }
#pragma unroll
        for (int kk = 0; kk < 4; ++kk) {
            const float4 wv = *(const float4*)(wbase + (k4 * 4 + kk) * 128 + c0);
#pragma unroll
            for (int i = 0; i < 8; ++i) {
                acc[i][0] += xs[i][kk] * wv.x;
                acc[i][1] += xs[i][kk] * wv.y;
                acc[i][2] += xs[i][kk] * wv.z;
                acc[i][3] += xs[i][kk] * wv.w;
            }
        }
    }
    if (mat == 0) {
        float* __restrict__ op = whs + (size_t)bt * 4096;
#pragma unroll
        for (int i = 0; i < 8; ++i) {
            float4 o; o.x = acc[i][0]; o.y = acc[i][1]; o.z = acc[i][2]; o.w = acc[i][3];
            *(float4*)(op + (r0 + i) * 64 + c0) = o;
        }
    } else {
        const float4 rb = *(const float4*)(res_b + c0);
        float* __restrict__ op = rs + (size_t)bt * 4096;
#pragma unroll
        for (int i = 0; i < 8; ++i) {
            float4 o; o.x = acc[i][0] + rb.x; o.y = acc[i][1] + rb.y;
            o.z = acc[i][2] + rb.z; o.w = acc[i][3] + rb.w;
            *(float4*)(op + (r0 + i) * 64 + c0) = o;
        }
    }
}

// ---------------------------------------------------------------- attention per (b,t)
// R13: Wh PV reads are WAVE-UNIFORM (base + j*64 + ha*16, ha const per wave) ->
// read straight from L1/L2-hot whs on the idle VMEM pipe instead of staging
// to LDS. LDS drops 36->20KB (8 blocks/CU, 32 waves) and the LDS pipe keeps
// only the cheap An/ej reads.
__global__ __launch_bounds__(256) void k_att(const float* __restrict__ ws,
                                             const float* __restrict__ whs,
                                             const float* __restrict__ rs,
                                             float* __restrict__ g,
                                             const float* __restrict__ gat_a,
                                             const float* __restrict__ ln_g,
                                             const float* __restrict__ ln_b) {
    __shared__ float sAn[64 * 65];
    __shared__ float sEjT[256];      // [h][j]
    __shared__ float sStat[64 * 8];  // [i][0:4]=sum partials, [i][4:8]=sumsq
    const int t = blockIdx.x, b = blockIdx.y, tid = threadIdx.x;
    const size_t bt = (size_t)(b * TT + t);
    const float* __restrict__ whb = whs + bt * 4096;
    // stage An
    const float* __restrict__ ang = ws + OFF_AN + (size_t)b * 4096;
    for (int i = tid; i < 4096; i += 256) sAn[(i >> 6) * 65 + (i & 63)] = ang[i];

    const int ia = tid & 63, ha = tid >> 6;
    // ei/ej from global Wh row (paid once per thread)
    float eiv = 0.f, ejv = 0.f;
    {
        const float* __restrict__ whrow = whb + ia * 64 + ha * 16;
        const float* __restrict__ aip = gat_a + ha * 32;
#pragma unroll
        for (int q = 0; q < 16; ++q) {
            const float w = whrow[q];
            eiv += w * aip[q];
            ejv += w * aip[16 + q];
        }
    }
    sEjT[ha * 64 + ia] = ejv;
    __syncthreads();  // sAn + sEjT visible

    // softmax + PV in registers; Wh fragments via wave-uniform global loads
    float ao[16];
#pragma unroll
    for (int f = 0; f < 16; ++f) ao[f] = 0.f;
    float sum = 0.f;
    const float* __restrict__ anrow = sAn + ia * 65;
    const float* __restrict__ ejrow = sEjT + ha * 64;
    const float* __restrict__ whp = whb + ha * 16;
#pragma unroll 4
    for (int j = 0; j < 64; ++j) {
        const float s = eiv + ejrow[j];
        const float l = s > 0.f ? s : 0.2f * s;
        const float anv = anrow[j];
        const float z = (anv != 0.f || j == ia) ? (l + anv) : -1e9f;
        const float p = __expf(z * INV_TEMP);
        sum += p;
        const float4 w0 = *(const float4*)(whp + j * 64);
        const float4 w1 = *(const float4*)(whp + j * 64 + 4);
        const float4 w2 = *(const float4*)(whp + j * 64 + 8);
        const float4 w3 = *(const float4*)(whp + j * 64 + 12);
        ao[0]  += p * w0.x; ao[1]  += p * w0.y; ao[2]  += p * w0.z; ao[3]  += p * w0.w;
        ao[4]  += p * w1.x; ao[5]  += p * w1.y; ao[6]  += p * w1.z; ao[7]  += p * w1.w;
        ao[8]  += p * w2.x; ao[9]  += p * w2.y; ao[10] += p * w2.z; ao[11] += p * w2.w;
        ao[12] += p * w3.x; ao[13] += p * w3.y; ao[14] += p * w3.z; ao[15] += p * w3.w;
    }
    const float inv = 1.f / sum;
    float val[16];
    float s1 = 0.f, s2 = 0.f;
    const float* __restrict__ rsp = rs + bt * 4096 + ia * 64 + ha * 16;
#pragma unroll
    for (int q = 0; q < 4; ++q) {
        const float4 rv = *(const float4*)(rsp + q * 4);
        val[q * 4 + 0] = ao[q * 4 + 0] * inv + rv.x;
        val[q * 4 + 1] = ao[q * 4 + 1] * inv + rv.y;
        val[q * 4 + 2] = ao[q * 4 + 2] * inv + rv.z;
        val[q * 4 + 3] = ao[q * 4 + 3] * inv + rv.w;
    }
#pragma unroll
    for (int f = 0; f < 16; ++f) { s1 += val[f]; s2 += val[f] * val[f]; }
    sStat[ia * 8 + ha] = s1;
    sStat[ia * 8 + 4 + ha] = s2;
    __syncthreads();
    const float tsum = sStat[ia * 8 + 0] + sStat[ia * 8 + 1] + sStat[ia * 8 + 2] + sStat[ia * 8 + 3];
    const float tsq  = sStat[ia * 8 + 4] + sStat[ia * 8 + 5] + sStat[ia * 8 + 6] + sStat[ia * 8 + 7];
    const float mean = tsum * (1.f / 64.f);
    const float var = tsq * (1.f / 64.f) - mean * mean;
    const float rstd = rsqrtf(var + 1e-5f);
    float* __restrict__ gout = g + bt * 4096 + ia * 64 + ha * 16;
#pragma unroll
    for (int q = 0; q < 4; ++q) {
        const float4 gm = *(const float4*)(ln_g + ha * 16 + q * 4);
        const float4 bt4 = *(const float4*)(ln_b + ha * 16 + q * 4);
        float4 o;
        o.x = fmaxf((val[q * 4 + 0] - mean) * rstd * gm.x + bt4.x, 0.f);
        o.y = fmaxf((val[q * 4 + 1] - mean) * rstd * gm.y + bt4.y, 0.f);
        o.z = fmaxf((val[q * 4 + 2] - mean) * rstd * gm.z + bt4.z, 0.f);
        o.w = fmaxf((val[q * 4 + 3] - mean) * rstd * gm.w + bt4.w, 0.f);
        *(float4*)(gout + q * 4) = o;
    }
}

// ---------------------------------------------------------------- zx GEMM: zx = g @ WihT + bias
__global__ __launch_bounds__(256) void k_zx(const float* __restrict__ gbuf,
                                            const float* __restrict__ ws,
                                            float* __restrict__ zx,
                                            const float* __restrict__ bihf, const float* __restrict__ bhhf,
                                            const float* __restrict__ bihb, const float* __restrict__ bhhb) {
    __shared__ __align__(16) float gS[128 * 68];
    const int mt2 = blockIdx.x, dir = blockIdx.y, tid = threadIdx.x;
    const float4* __restrict__ gsrc4 = (const float4*)(gbuf + (size_t)mt2 * 8192);
    for (int i4 = tid; i4 < 2048; i4 += 256) {
        const int row = i4 >> 4, c4 = i4 & 15;
        *(float4*)&gS[row * 68 + c4 * 4] = gsrc4[i4];
    }
    __syncthreads();
    const int ty = tid >> 4, cxx = tid & 15;
    const int c0 = cxx * 8;
    const float* __restrict__ wT = ws + OFF_WIHT + (size_t)dir * 8192;
    float acc[8][8];
#pragma unroll
    for (int i = 0; i < 8; ++i)
#pragma unroll
        for (int j = 0; j < 8; ++j) acc[i][j] = 0.f;
    for (int k4 = 0; k4 < 16; ++k4) {
        float xs[8][4];
#pragma unroll
        for (int i = 0; i < 8; ++i) {
            const float4 v = *(const float4*)&gS[(ty + 16 * i) * 68 + k4 * 4];
            xs[i][0] = v.x; xs[i][1] = v.y; xs[i][2] = v.z; xs[i][3] = v.w;
        }
#pragma unroll
        for (int kk = 0; kk < 4; ++kk) {
            const float4 w0 = *(const float4*)(wT + (k4 * 4 + kk) * 128 + c0);
            const float4 w1 = *(const float4*)(wT + (k4 * 4 + kk) * 128 + c0 + 4);
#pragma unroll
            for (int i = 0; i < 8; ++i) {
                const float xv = xs[i][kk];
                acc[i][0] += xv * w0.x; acc[i][1] += xv * w0.y;
                acc[i][2] += xv * w0.z; acc[i][3] += xv * w0.w;
                acc[i][4] += xv * w1.x; acc[i][5] += xv * w1.y;
                acc[i][6] += xv * w1.z; acc[i][7] += xv * w1.w;
            }
        }
    }
    const float* bi = dir ? bihb : bihf;
    const float* bh = dir ? bhhb : bhhf;
    float bsum[8];
    {
        const float4 b0 = *(const float4*)(bi + c0), b1 = *(const float4*)(bi + c0 + 4);
        const float4 h0 = *(const float4*)(bh + c0), h1 = *(const float4*)(bh + c0 + 4);
        bsum[0] = b0.x + h0.x; bsum[1] = b0.y + h0.y; bsum[2] = b0.z + h0.z; bsum[3] = b0.w + h0.w;
        bsum[4] = b1.x + h1.x; bsum[5] = b1.y + h1.y; bsum[6] = b1.z + h1.z; bsum[7] = b1.w + h1.w;
    }
    float* __restrict__ zrow = zx + (size_t)dir * 16777216 + (size_t)mt2 * 16384;
#pragma unroll
    for (int i = 0; i < 8; ++i) {
        const int r = ty + 16 * i;
        float4 o0, o1;
        o0.x = acc[i][0] + bsum[0]; o0.y = acc[i][1] + bsum[1];
        o0.z = acc[i][2] + bsum[2]; o0.w = acc[i][3] + bsum[3];
        o1.x = acc[i][4] + bsum[4]; o1.y = acc[i][5] + bsum[5];
        o1.z = acc[i][6] + bsum[6]; o1.w = acc[i][7] + bsum[7];
        *(float4*)&zrow[r * 128 + c0] = o0;
        *(float4*)&zrow[r * 128 + c0 + 4] = o1;
    }
}

// ---------------------------------------------------------------- single-wave recurrent LSTM
__device__ __forceinline__ float rl(float v, int l) {
    return __int_as_float(__builtin_amdgcn_readlane(__float_as_int(v), l));
}

// Best measured variant (R6/R10/R12: 131-133us). R7-R11 established ~132us as
// the compiler's register-policy floor for this shape. Do not re-litigate.
__global__ __launch_bounds__(64, 1) void k_lstm2(const float* __restrict__ zx,
                                                 float* __restrict__ hbuf,
                                                 const float* __restrict__ Whhf,
                                                 const float* __restrict__ Whhb) {
    const int n = blockIdx.x, dir = blockIdx.y, r = threadIdx.x;
    const bool lo = (r < 32);
    const float* __restrict__ Whh = dir ? Whhb : Whhf;
    const float4* W4 = (const float4*)Whh;
    const float4 wa0 = W4[r * 8 + 0], wa1 = W4[r * 8 + 1], wa2 = W4[r * 8 + 2], wa3 = W4[r * 8 + 3];
    const float4 wa4 = W4[r * 8 + 4], wa5 = W4[r * 8 + 5], wa6 = W4[r * 8 + 6], wa7 = W4[r * 8 + 7];
    const float4 wb0 = W4[(r + 64) * 8 + 0], wb1 = W4[(r + 64) * 8 + 1];
    const float4 wb2 = W4[(r + 64) * 8 + 2], wb3 = W4[(r + 64) * 8 + 3];
    const float4 wb4 = W4[(r + 64) * 8 + 4], wb5 = W4[(r + 64) * 8 + 5];
    const float4 wb6 = W4[(r + 64) * 8 + 6], wb7 = W4[(r + 64) * 8 + 7];
    const float* __restrict__ zxp = zx + (size_t)dir * 16777216 + (size_t)n * 16384;
    float* __restrict__ hout = hbuf + (size_t)n * 8192 + dir * 32 + r;
    float hv = 0.f, cv = 0.f;

#define SADDR(S_) (zxp + (size_t)(dir ? 127 - (S_) : (S_)) * 128)
#define DOT4(Q) {                                                           \
        const float h0 = rl(hv, 4 * Q + 0), h1 = rl(hv, 4 * Q + 1);         \
        const float h2 = rl(hv, 4 * Q + 2), h3 = rl(hv, 4 * Q + 3);         \
        a0 += h0 * wa##Q.x; b0 += h0 * wb##Q.x;                             \
        a1 += h1 * wa##Q.y; b1 += h1 * wb##Q.y;                             \
        a0 += h2 * wa##Q.z; b0 += h2 * wb##Q.z;                             \
        a1 += h3 * wa##Q.w; b1 += h3 * wb##Q.w;                             \
    }
#define STEP(S_, ZA, ZB) {                                                  \
        float a0 = (ZA), a1 = 0.f, b0 = (ZB), b1 = 0.f;                     \
        DOT4(0) DOT4(1) DOT4(2) DOT4(3) DOT4(4) DOT4(5) DOT4(6) DOT4(7)    \
        const float zi = a0 + a1, zg = b0 + b1;                             \
        const float eA = __expf(-zi);                                       \
        const float sA = 1.f / (1.f + eA);                                  \
        const float eB = __expf(lo ? -2.f * zg : -zg);                      \
        const float vB = lo ? (2.f / (1.f + eB) - 1.f) : (1.f / (1.f + eB));\
        const float fv = __shfl_xor(sA, 32);                                \
        const float ox = __shfl_xor(vB, 32);                                \
        cv = fv * cv + sA * vB;                                             \
        const float eC = __expf(-2.f * cv);                                 \
        const float tc = 2.f / (1.f + eC) - 1.f;                            \
        hv = ox * tc;                                                       \
        const int s__ = dir ? 127 - (S_) : (S_);                            \
        if (lo) hout[s__ * 64] = hv;                                        \
    }

    const float* p0 = SADDR(0);
    const float* p1 = SADDR(1);
    float zA0 = p0[r], zB0 = p0[r + 64];
    float zA1 = p1[r], zB1 = p1[r + 64];
    for (int s2 = 0; s2 < 64; ++s2) {
        int sp = 2 * s2 + 2; if (sp > 126) sp = 126;
        const float* pn0 = SADDR(sp);
        const float* pn1 = SADDR(sp + 1);
        const float nA0 = pn0[r], nB0 = pn0[r + 64];
        const float nA1 = pn1[r], nB1 = pn1[r + 64];
        STEP(2 * s2, zA0, zB0);
        STEP(2 * s2 + 1, zA1, zB1);
        zA0 = nA0; zB0 = nB0; zA1 = nA1; zB1 = nB1;
    }
#undef STEP
#undef DOT4
#undef SADDR
}

// ---------------------------------------------------------------- temporal attention per n
__global__ __launch_bounds__(256) void k_ta(float* __restrict__ ws,
                                            const float* __restrict__ tab,
                                            const float* __restrict__ tav) {
    __shared__ __align__(16) float hL[128 * 68];
    __shared__ float scL[128];
    __shared__ float sRed[4];
    __shared__ float sPart[256];
    const int n = blockIdx.x, tid = threadIdx.x, lane = tid & 63, wave = tid >> 6;
    const float4* __restrict__ hsrc4 = (const float4*)(ws + OFF_H + (size_t)n * 8192);
    for (int i4 = tid; i4 < 2048; i4 += 256) {
        const int row = i4 >> 4, c4 = i4 & 15;
        *(float4*)&hL[row * 68 + c4 * 4] = hsrc4[i4];
    }
    __syncthreads();
    const int ty8 = lane >> 3, ux = lane & 7;
    const int t0 = wave * 32 + ty8, u0 = ux * 8;
    const float* __restrict__ twt = ws + OFF_TAWT;
    float tb[8], tv[8];
    *(float4*)&tb[0] = *(const float4*)(tab + u0);
    *(float4*)&tb[4] = *(const float4*)(tab + u0 + 4);
    *(float4*)&tv[0] = *(const float4*)(tav + u0);
    *(float4*)&tv[4] = *(const float4*)(tav + u0 + 4);
    float a[4][8];
#pragma unroll
    for (int i = 0; i < 4; ++i)
#pragma unroll
        for (int j = 0; j < 8; ++j) a[i][j] = 0.f;
    for (int v4 = 0; v4 < 16; ++v4) {
        float xs[4][4];
#pragma unroll
        for (int i = 0; i < 4; ++i) {
            const float4 v = *(const float4*)&hL[(t0 + 8 * i) * 68 + v4 * 4];
            xs[i][0] = v.x; xs[i][1] = v.y; xs[i][2] = v.z; xs[i][3] = v.w;
        }
#pragma unroll
        for (int kk = 0; kk < 4; ++kk) {
            const float4 w0 = *(const float4*)(twt + (v4 * 4 + kk) * 64 + u0);
            const float4 w1 = *(const float4*)(twt + (v4 * 4 + kk) * 64 + u0 + 4);
#pragma unroll
            for (int i = 0; i < 4; ++i) {
                const float xv = xs[i][kk];
                a[i][0] += xv * w0.x; a[i][1] += xv * w0.y;
                a[i][2] += xv * w0.z; a[i][3] += xv * w0.w;
                a[i][4] += xv * w1.x; a[i][5] += xv * w1.y;
                a[i][6] += xv * w1.z; a[i][7] += xv * w1.w;
            }
        }
    }
#pragma unroll
    for (int i = 0; i < 4; ++i) {
        float s = 0.f;
#pragma unroll
        for (int u = 0; u < 8; ++u) s += tanhf(a[i][u] + tb[u]) * tv[u];
        s += __shfl_xor(s, 1); s += __shfl_xor(s, 2); s += __shfl_xor(s, 4);
        if (ux == 0) scL[t0 + 8 * i] = s;
    }
    __syncthreads();
    const float v = (tid < 128) ? scL[tid] : -1e30f;
    float mw = v;
    mw = fmaxf(mw, __shfl_xor(mw, 1)); mw = fmaxf(mw, __shfl_xor(mw, 2));
    mw = fmaxf(mw, __shfl_xor(mw, 4)); mw = fmaxf(mw, __shfl_xor(mw, 8));
    mw = fmaxf(mw, __shfl_xor(mw, 16)); mw = fmaxf(mw, __shfl_xor(mw, 32));
    if (lane == 0) sRed[wave] = mw;
    __syncthreads();
    const float m = fmaxf(fmaxf(sRed[0], sRed[1]), fmaxf(sRed[2], sRed[3]));
    const float p = (tid < 128) ? __expf((v - m) * INV_TEMP) : 0.f;
    float sw = p;
    sw += __shfl_xor(sw, 1); sw += __shfl_xor(sw, 2); sw += __shfl_xor(sw, 4);
    sw += __shfl_xor(sw, 8); sw += __shfl_xor(sw, 16); sw += __shfl_xor(sw, 32);
    __syncthreads();
    if (lane == 0) sRed[wave] = sw;
    __syncthreads();
    const float stot = sRed[0] + sRed[1] + sRed[2] + sRed[3];
    if (tid < 128) scL[tid] = p / stot;
    __syncthreads();
    float part = 0.f;
    for (int tt = 0; tt < 32; ++tt) {
        const int t = wave * 32 + tt;
        part += scL[t] * hL[t * 68 + lane];
    }
    sPart[wave * 64 + lane] = part;
    __syncthreads();
    if (tid < 64)
        ws[OFF_HP + (size_t)n * 64 + tid] =
            sPart[tid] + sPart[64 + tid] + sPart[128 + tid] + sPart[192 + tid];
}

// ---------------------------------------------------------------- channel attn + LN + MLP per b
__global__ __launch_bounds__(64) void k_final(const float* __restrict__ ws,
                                              const float* __restrict__ cpW, const float* __restrict__ cpb,
                                              const float* __restrict__ ng, const float* __restrict__ nb,
                                              const float* __restrict__ f1W, const float* __restrict__ f1b,
                                              const float* __restrict__ f2W, const float* __restrict__ f2b,
                                              float* __restrict__ out) {
    __shared__ float xc[64 * 65];
    __shared__ float wL[64];
    __shared__ float plL[64];
    __shared__ float h1L[32];
    const int b = blockIdx.x, tid = threadIdx.x;
    const float* hp = ws + OFF_HP + (size_t)b * 4096;
    for (int m = 0; m < 64; ++m) xc[m * 65 + tid] = hp[m * 64 + tid];
    __syncthreads();
    float s = cpb[0];
    for (int j = 0; j < 64; ++j) s += xc[tid * 65 + j] * cpW[j];
    float mm = s;
    for (int o = 1; o < 64; o <<= 1) mm = fmaxf(mm, __shfl_xor(mm, o));
    const float p = __expf(s - mm);
    float sum = p;
    for (int o = 1; o < 64; o <<= 1) sum += __shfl_xor(sum, o);
    wL[tid] = p / sum;
    __syncthreads();
    float pool = 0.f;
    for (int c = 0; c < 64; ++c) pool += xc[c * 65 + tid] * wL[c];
    float ms = pool;
    for (int o = 1; o < 64; o <<= 1) ms += __shfl_xor(ms, o);
    const float mean = ms * (1.f / 64.f);
    const float d = pool - mean;
    float vv = d * d;
    for (int o = 1; o < 64; o <<= 1) vv += __shfl_xor(vv, o);
    const float pl = d * rsqrtf(vv * (1.f / 64.f) + 1e-5f) * ng[tid] + nb[tid];
    plL[tid] = pl;
    __syncthreads();
    if (tid < 32) {
        float h1 = f1b[tid];
        for (int j = 0; j < 64; ++j) h1 += plL[j] * f1W[tid * 64 + j];
        h1L[tid] = fmaxf(h1, 0.f);
    }
    __syncthreads();
    if (tid < 3) {
        float o = f2b[tid];
        for (int uu = 0; uu < 32; ++uu) o += h1L[uu] * f2W[tid * 32 + uu];
        out[b * 3 + tid] = o;
    }
}

// ---------------------------------------------------------------- launch
extern "C" void kernel_launch(void* const* d_in, const int* in_sizes, int n_in,
                              void* d_out, int out_size, void* d_ws, size_t ws_size,
                              hipStream_t stream) {
    (void)in_sizes; (void)n_in; (void)out_size; (void)ws_size;
    const float* x      = (const float*)d_in[0];
    const float* spec_w = (const float*)d_in[1];
    const float* gat_W  = (const float*)d_in[2];
    const float* gat_a  = (const float*)d_in[3];
    const float* gat_ng = (const float*)d_in[4];
    const float* gat_nb = (const float*)d_in[5];
    const float* gat_rW = (const float*)d_in[6];
    const float* gat_rb = (const float*)d_in[7];
    const float* Wihf   = (const float*)d_in[8];
    const float* Whhf   = (const float*)d_in[9];
    const float* bihf   = (const float*)d_in[10];
    const float* bhhf   = (const float*)d_in[11];
    const float* Wihb   = (const float*)d_in[12];
    const float* Whhb   = (const float*)d_in[13];
    const float* bihb   = (const float*)d_in[14];
    const float* bhhb   = (const float*)d_in[15];
    const float* ta_W   = (const float*)d_in[16];
    const float* ta_b   = (const float*)d_in[17];
    const float* ta_v   = (const float*)d_in[18];
    const float* cp_W   = (const float*)d_in[19];
    const float* cp_b   = (const float*)d_in[20];
    const float* norm_g = (const float*)d_in[21];
    const float* norm_b = (const float*)d_in[22];
    const float* fc1_W  = (const float*)d_in[23];
    const float* fc1_b  = (const float*)d_in[24];
    const float* fc2_W  = (const float*)d_in[25];
    const float* fc2_b  = (const float*)d_in[26];
    float* ws  = (float*)d_ws;
    float* out = (float*)d_out;

    hipLaunchKernelGGL(k_prep, dim3(144), dim3(256), 0, stream, gat_W, gat_rW, ta_W, Wihf, Wihb, ws);
    hipLaunchKernelGGL(k_corr, dim3(64, 16), dim3(256), 0, stream, x, spec_w, ws);
    hipLaunchKernelGGL(k_reduceA, dim3(256), dim3(256), 0, stream, ws);
    hipLaunchKernelGGL(k_sparsify, dim3(16), dim3(64), 0, stream, ws);
    hipLaunchKernelGGL(k_wh, dim3(2048), dim3(256), 0, stream,
                       x, spec_w, ws + OFF_WRT,
                       ws + OFF_WHS, ws + OFF_RS, gat_rb);
    hipLaunchKernelGGL(k_att, dim3(128, 16), dim3(256), 0, stream,
                       ws, ws + OFF_WHS, ws + OFF_RS, ws + OFF_G,
                       gat_a, gat_ng, gat_nb);
    hipLaunchKernelGGL(k_zx, dim3(1024, 2), dim3(256), 0, stream,
                       ws + OFF_G, ws, ws + OFF_ZX, bihf, bhhf, bihb, bhhb);
    hipLaunchKernelGGL(k_lstm2, dim3(1024, 2), dim3(64), 0, stream,
                       ws + OFF_ZX, ws + OFF_H, Whhf, Whhb);
    hipLaunchKernelGGL(k_ta, dim3(1024), dim3(256), 0, stream, ws, ta_b, ta_v);
    hipLaunchKernelGGL(k_final, dim3(16), dim3(64), 0, stream, ws, cp_W, cp_b,
                       norm_g, norm_b, fc1_W, fc1_b, fc2_W, fc2_b, out);
}

// Round 14
// 413.996 us; speedup vs baseline: 1.1044x; 1.1044x over previous
//
#include <hip/hip_runtime.h>
#include <math.h>

// ---- model sizes ----
#define BB 16
#define TT 128
#define CC 64
#define FF 128
// H=4, FO=16, H*FO=64, HID=32

static constexpr float INV_TEMP = 1.0f / 1.5f;

// ---- workspace offsets (in floats) ----
static constexpr size_t OFF_WTT   = 8192;       //  8192  WT[k][g]  (gat_W transposed)
static constexpr size_t OFF_RTT   = 16384;      //  8192  RT[k][g]  (gat_res_W transposed)
static constexpr size_t OFF_TAWT  = 24576;      //  4096  taWT[v][u]
static constexpr size_t OFF_AN    = 28672;      // 65536  An[b][i][j] row-major
static constexpr size_t OFF_A     = 94208;      // 65536  A[b][c][d]
static constexpr size_t OFF_G     = 1208320;    // 8388608 GAT output [b][t][c][64]
static constexpr size_t OFF_H     = 9596928;    // 8388608 BiLSTM out [n][tau][64]
static constexpr size_t OFF_HP    = 17985536;   // 65536  pooled [n][64]
static constexpr size_t OFF_WIHT  = 18051072;   // 16384  WihT[dir][64k][128g]
static constexpr size_t OFF_ZX    = 18067456;   // 33554432 zx[dir][n*128+t][128]
// aliases inside ZX region (all dead before k_zx runs):
static constexpr size_t OFF_WHS   = OFF_ZX + 16777216;  //  8388608: Wh [bt][64][64]
static constexpr size_t OFF_RS    = OFF_ZX + 25165824;  //  8388608: res+bias [bt][64][64]
// APART (corr partials) aliases the WHS region: alive only corr -> reduceA.
static constexpr size_t OFF_APART = OFF_WHS;            //  4194304 floats used

// ---------------------------------------------------------------- prep: weight transposes
__global__ __launch_bounds__(256) void k_prep(const float* __restrict__ gat_W,
                                              const float* __restrict__ gat_rW,
                                              const float* __restrict__ ta_W,
                                              const float* __restrict__ Wihf,
                                              const float* __restrict__ Wihb,
                                              float* __restrict__ ws) {
    int i = blockIdx.x * 256 + threadIdx.x;  // < 36864, grid 144
    if (i < 8192) {
        int k = i >> 6, g = i & 63;
        ws[OFF_WTT + i] = gat_W[g * 128 + k];
    } else if (i < 16384) {
        int j = i - 8192; int k = j >> 6, g = j & 63;
        ws[OFF_RTT + j] = gat_rW[g * 128 + k];
    } else if (i < 20480) {
        int j = i - 16384; int v = j >> 6, u = j & 63;
        ws[OFF_TAWT + j] = ta_W[u * 64 + v];
    } else if (i < 36864) {
        int j = i - 20480;  // WihT[dir][k][g] = Wih_dir[g][k]
        int dir = j >> 13, rem = j & 8191, k = rem >> 7, gg = rem & 127;
        const float* W = dir ? Wihb : Wihf;
        ws[OFF_WIHT + j] = W[gg * 64 + k];
    }
}

__device__ __forceinline__ float4 sigmul4(const float4 xv, const float4 wv) {
    float4 o;
    o.x = xv.x / (1.f + __expf(-wv.x));
    o.y = xv.y / (1.f + __expf(-wv.y));
    o.z = xv.z / (1.f + __expf(-wv.z));
    o.w = xv.w / (1.f + __expf(-wv.w));
    return o;
}

// ---------------------------------------------------------------- corr partial grams (R11-measured)
__global__ __launch_bounds__(256) void k_corr(const float* __restrict__ x,
                                              const float* __restrict__ spec_w,
                                              float* __restrict__ ws) {
    __shared__ __align__(16) float tile[64 * 132];
    __shared__ float rn[64];
    const int ch = blockIdx.x, b = blockIdx.y, tid = threadIdx.x;
    const int lane = tid & 63, wave = tid >> 6;
    const int c0 = wave * 16 + ((lane >> 4) << 2);
    const int d0 = (lane & 15) << 2;
    const float4* __restrict__ sg4 = (const float4*)spec_w;
    float acc[4][4];
#pragma unroll
    for (int a = 0; a < 4; ++a)
#pragma unroll
        for (int e = 0; e < 4; ++e) acc[a][e] = 0.f;

    for (int t8 = 0; t8 < 2; ++t8) {
        const int t = ch * 2 + t8;
        __syncthreads();
        const float4* __restrict__ xp4 = (const float4*)(x + ((size_t)(b * TT + t)) * CC * FF);
        for (int i4 = tid; i4 < 2048; i4 += 256) {
            const int row = i4 >> 5, col4 = i4 & 31;
            *(float4*)&tile[row * 132 + col4 * 4] = sigmul4(xp4[i4], sg4[i4]);
        }
        __syncthreads();
        {   // row norms: 4 threads per row
            const int row = tid >> 2, part = tid & 3;
            const float4* tr = (const float4*)(tile + row * 132 + part * 32);
            float s = 0.f;
#pragma unroll
            for (int q = 0; q < 8; ++q) {
                const float4 v = tr[q];
                s += v.x * v.x + v.y * v.y + v.z * v.z + v.w * v.w;
            }
            s += __shfl_xor(s, 1); s += __shfl_xor(s, 2);
            if (part == 0) rn[row] = 1.f / (sqrtf(s) + 1e-8f);
        }
        __syncthreads();
        float dot[4][4];
#pragma unroll
        for (int a = 0; a < 4; ++a)
#pragma unroll
            for (int e = 0; e < 4; ++e) dot[a][e] = 0.f;
        for (int f4 = 0; f4 < 32; ++f4) {
            float4 xc4[4], xd4[4];
#pragma unroll
            for (int a = 0; a < 4; ++a) xc4[a] = *(const float4*)&tile[(c0 + a) * 132 + f4 * 4];
#pragma unroll
            for (int e = 0; e < 4; ++e) xd4[e] = *(const float4*)&tile[(d0 + e) * 132 + f4 * 4];
#pragma unroll
            for (int a = 0; a < 4; ++a)
#pragma unroll
                for (int e = 0; e < 4; ++e)
                    dot[a][e] += xc4[a].x * xd4[e].x + xc4[a].y * xd4[e].y +
                                 xc4[a].z * xd4[e].z + xc4[a].w * xd4[e].w;
        }
#pragma unroll
        for (int a = 0; a < 4; ++a) {
            const float ra = rn[c0 + a];
#pragma unroll
            for (int e = 0; e < 4; ++e) acc[a][e] += ra * rn[d0 + e] * dot[a][e];
        }
    }
    float* __restrict__ Ap = ws + OFF_APART + ((size_t)(b * 64 + ch)) * 4096;
#pragma unroll
    for (int a = 0; a < 4; ++a)
#pragma unroll
        for (int e = 0; e < 4; ++e) Ap[(c0 + a) * 64 + d0 + e] = acc[a][e];
}

// ---------------------------------------------------------------- reduce A (deterministic)
__global__ __launch_bounds__(256) void k_reduceA(float* __restrict__ ws) {
    int i = blockIdx.x * 256 + threadIdx.x;  // < 65536
    int b = i >> 12, e = i & 4095;
    const float* Ap = ws + OFF_APART + (size_t)b * 64 * 4096;
    float s = 0.f;
#pragma unroll 8
    for (int ch = 0; ch < 64; ++ch) s += Ap[ch * 4096 + e];
    ws[OFF_A + i] = s * (1.f / 128.f);
}

// ---------------------------------------------------------------- top-k sparsify -> An[i][j]
__global__ __launch_bounds__(64) void k_sparsify(float* __restrict__ ws) {
    __shared__ float As[64 * 65];
    __shared__ unsigned char kp[64 * 64];
    const int b = blockIdx.x, tid = threadIdx.x;  // 64 threads
    const float* Ag = ws + OFF_A + (size_t)b * 4096;
    for (int m = 0; m < 64; ++m) As[m * 65 + tid] = Ag[m * 64 + tid];
    __syncthreads();
    const int c = tid;
    int s0 = -1, s1 = -1, s2 = -1;
    for (int p = 0; p < 3; ++p) {
        float best = -1e30f; int bi = -1;
        for (int d = 0; d < 64; ++d) {
            if (d == s0 || d == s1) continue;
            float v = As[c * 65 + d];
            if (v > best) { best = v; bi = d; }
        }
        if (p == 0) s0 = bi; else if (p == 1) s1 = bi; else s2 = bi;
    }
    for (int d = 0; d < 64; ++d) {
        float v = As[c * 65 + d];
        kp[c * 64 + d] = (unsigned char)(((d == s0) | (d == s1) | (d == s2)) &&
                                         (v > 0.3f) && (d != c));
    }
    __syncthreads();
    float rs = 0.f;
    for (int d = 0; d < 64; ++d) {
        bool k2 = kp[c * 64 + d] || kp[d * 64 + c];
        rs += k2 ? As[c * 65 + d] : 0.f;
    }
    const float inv = 1.f / (rs + 1e-8f);
    float* An = ws + OFF_AN + (size_t)b * 4096;
    for (int d = 0; d < 64; ++d) {
        bool k2 = kp[c * 64 + d] || kp[d * 64 + c];
        An[c * 64 + d] = k2 ? As[c * 65 + d] * inv : 0.f;  // row-major [i][j]
    }
}

// ---------------------------------------------------------------- batched GEMM (R11-measured: 8x4 tile)
__global__ __launch_bounds__(256) void k_wh(const float* __restrict__ x,
                                            const float* __restrict__ spec_w,
                                            const float* __restrict__ wt,
                                            const float* __restrict__ rt,
                                            float* __restrict__ whs,
                                            float* __restrict__ rs,
                                            const float* __restrict__ res_b) {
    __shared__ __align__(16) float tile[64 * 132];
    const int bt = blockIdx.x, tid = threadIdx.x;
    const float4* __restrict__ xp4 = (const float4*)(x + (size_t)bt * 8192);
    const float4* __restrict__ sg4 = (const float4*)spec_w;
    for (int i4 = tid; i4 < 2048; i4 += 256) {
        const int row = i4 >> 5, col4 = i4 & 31;
        *(float4*)&tile[row * 132 + col4 * 4] = sigmul4(xp4[i4], sg4[i4]);
    }
    __syncthreads();
    const int tx = tid & 31, ty = tid >> 5;
    const int mat = tx >> 4, cx = tx & 15;
    const int r0 = ty * 8, c0 = cx * 4;
    const float* __restrict__ wbase = mat ? rt : wt;
    float acc[8][4];
#pragma unroll
    for (int i = 0; i < 8; ++i)
#pragma unroll
        for (int j = 0; j < 4; ++j) acc[i][j] = 0.f;
    for (int k4 = 0; k4 < 32; ++k4) {
        float xs[8][4];
#pragma unroll
        for (int i = 0; i < 8; ++i) {
            const float4 v = *(const float4*)&tile[(r0 + i) * 132 + k4 * 4];
            xs[i][0] = v.x; xs[i][1] = v.y; xs[i][2] = v.z; xs[i][3] = v.w;
        }
#pragma unroll
        for (int kk = 0; kk < 4; ++kk) {
            const float4 wv = *(const float4*)(wbase + (k4 * 4 + kk) * 64 + c0);
#pragma unroll
            for (int i = 0; i < 8; ++i) {
                acc[i][0] += xs[i][kk] * wv.x;
                acc[i][1] += xs[i][kk] * wv.y;
                acc[i][2] += xs[i][kk] * wv.z;
                acc[i][3] += xs[i][kk] * wv.w;
            }
        }
    }
    if (mat == 0) {
        float* __restrict__ op = whs + (size_t)bt * 4096;
#pragma unroll
        for (int i = 0; i < 8; ++i) {
            float4 o; o.x = acc[i][0]; o.y = acc[i][1]; o.z = acc[i][2]; o.w = acc[i][3];
            *(float4*)(op + (r0 + i) * 64 + c0) = o;
        }
    } else {
        const float4 rb = *(const float4*)(res_b + c0);
        float* __restrict__ op = rs + (size_t)bt * 4096;
#pragma unroll
        for (int i = 0; i < 8; ++i) {
            float4 o; o.x = acc[i][0] + rb.x; o.y = acc[i][1] + rb.y;
            o.z = acc[i][2] + rb.z; o.w = acc[i][3] + rb.w;
            *(float4*)(op + (r0 + i) * 64 + c0) = o;
        }
    }
}

// ---------------------------------------------------------------- attention per (b,t) (R11-measured: sWh LDS-staged)
__global__ __launch_bounds__(256) void k_att(const float* __restrict__ ws,
                                             const float* __restrict__ whs,
                                             const float* __restrict__ rs,
                                             float* __restrict__ g,
                                             const float* __restrict__ gat_a,
                                             const float* __restrict__ ln_g,
                                             const float* __restrict__ ln_b) {
    __shared__ __align__(16) float sWh[64 * 68];
    __shared__ float sAn[64 * 65];
    __shared__ float sEjT[256];   // [h][j]
    __shared__ float sStat[64 * 8];  // [i][0:4]=sum partials, [i][4:8]=sumsq
    const int t = blockIdx.x, b = blockIdx.y, tid = threadIdx.x;
    const size_t bt = (size_t)(b * TT + t);
    const float4* __restrict__ wh4 = (const float4*)(whs + bt * 4096);
    for (int i4 = tid; i4 < 1024; i4 += 256) {
        const int row = i4 >> 4, c4 = i4 & 15;
        *(float4*)&sWh[row * 68 + c4 * 4] = wh4[i4];
    }
    const float* __restrict__ ang = ws + OFF_AN + (size_t)b * 4096;
    for (int i = tid; i < 4096; i += 256) sAn[(i >> 6) * 65 + (i & 63)] = ang[i];
    __syncthreads();

    const int ia = tid & 63, ha = tid >> 6;
    float eiv = 0.f, ejv = 0.f;
    {
        const float* __restrict__ whrow = sWh + ia * 68 + ha * 16;
        const float* __restrict__ aip = gat_a + ha * 32;
#pragma unroll
        for (int q = 0; q < 16; ++q) {
            const float w = whrow[q];
            eiv += w * aip[q];
            ejv += w * aip[16 + q];
        }
    }
    sEjT[ha * 64 + ia] = ejv;
    __syncthreads();

    float ao[16];
#pragma unroll
    for (int f = 0; f < 16; ++f) ao[f] = 0.f;
    float sum = 0.f;
    const float* __restrict__ anrow = sAn + ia * 65;
    const float* __restrict__ ejrow = sEjT + ha * 64;
#pragma unroll 4
    for (int j = 0; j < 64; ++j) {
        const float s = eiv + ejrow[j];
        const float l = s > 0.f ? s : 0.2f * s;
        const float anv = anrow[j];
        const float z = (anv != 0.f || j == ia) ? (l + anv) : -1e9f;
        const float p = __expf(z * INV_TEMP);
        sum += p;
        const float* __restrict__ wj = sWh + j * 68 + ha * 16;
        const float4 w0 = *(const float4*)(wj);
        const float4 w1 = *(const float4*)(wj + 4);
        const float4 w2 = *(const float4*)(wj + 8);
        const float4 w3 = *(const float4*)(wj + 12);
        ao[0]  += p * w0.x; ao[1]  += p * w0.y; ao[2]  += p * w0.z; ao[3]  += p * w0.w;
        ao[4]  += p * w1.x; ao[5]  += p * w1.y; ao[6]  += p * w1.z; ao[7]  += p * w1.w;
        ao[8]  += p * w2.x; ao[9]  += p * w2.y; ao[10] += p * w2.z; ao[11] += p * w2.w;
        ao[12] += p * w3.x; ao[13] += p * w3.y; ao[14] += p * w3.z; ao[15] += p * w3.w;
    }
    const float inv = 1.f / sum;
    float val[16];
    float s1 = 0.f, s2 = 0.f;
    const float* __restrict__ rsp = rs + bt * 4096 + ia * 64 + ha * 16;
#pragma unroll
    for (int q = 0; q < 4; ++q) {
        const float4 rv = *(const float4*)(rsp + q * 4);
        val[q * 4 + 0] = ao[q * 4 + 0] * inv + rv.x;
        val[q * 4 + 1] = ao[q * 4 + 1] * inv + rv.y;
        val[q * 4 + 2] = ao[q * 4 + 2] * inv + rv.z;
        val[q * 4 + 3] = ao[q * 4 + 3] * inv + rv.w;
    }
#pragma unroll
    for (int f = 0; f < 16; ++f) { s1 += val[f]; s2 += val[f] * val[f]; }
    sStat[ia * 8 + ha] = s1;
    sStat[ia * 8 + 4 + ha] = s2;
    __syncthreads();
    const float tsum = sStat[ia * 8 + 0] + sStat[ia * 8 + 1] + sStat[ia * 8 + 2] + sStat[ia * 8 + 3];
    const float tsq  = sStat[ia * 8 + 4] + sStat[ia * 8 + 5] + sStat[ia * 8 + 6] + sStat[ia * 8 + 7];
    const float mean = tsum * (1.f / 64.f);
    const float var = tsq * (1.f / 64.f) - mean * mean;
    const float rstd = rsqrtf(var + 1e-5f);
    float* __restrict__ gout = g + bt * 4096 + ia * 64 + ha * 16;
#pragma unroll
    for (int q = 0; q < 4; ++q) {
        const float4 gm = *(const float4*)(ln_g + ha * 16 + q * 4);
        const float4 bt4 = *(const float4*)(ln_b + ha * 16 + q * 4);
        float4 o;
        o.x = fmaxf((val[q * 4 + 0] - mean) * rstd * gm.x + bt4.x, 0.f);
        o.y = fmaxf((val[q * 4 + 1] - mean) * rstd * gm.y + bt4.y, 0.f);
        o.z = fmaxf((val[q * 4 + 2] - mean) * rstd * gm.z + bt4.z, 0.f);
        o.w = fmaxf((val[q * 4 + 3] - mean) * rstd * gm.w + bt4.w, 0.f);
        *(float4*)(gout + q * 4) = o;
    }
}

// ---------------------------------------------------------------- zx GEMM: zx = g @ WihT + bias
__global__ __launch_bounds__(256) void k_zx(const float* __restrict__ gbuf,
                                            const float* __restrict__ ws,
                                            float* __restrict__ zx,
                                            const float* __restrict__ bihf, const float* __restrict__ bhhf,
                                            const float* __restrict__ bihb, const float* __restrict__ bhhb) {
    __shared__ __align__(16) float gS[128 * 68];
    const int mt2 = blockIdx.x, dir = blockIdx.y, tid = threadIdx.x;
    const float4* __restrict__ gsrc4 = (const float4*)(gbuf + (size_t)mt2 * 8192);
    for (int i4 = tid; i4 < 2048; i4 += 256) {
        const int row = i4 >> 4, c4 = i4 & 15;
        *(float4*)&gS[row * 68 + c4 * 4] = gsrc4[i4];
    }
    __syncthreads();
    const int ty = tid >> 4, cxx = tid & 15;
    const int c0 = cxx * 8;
    const float* __restrict__ wT = ws + OFF_WIHT + (size_t)dir * 8192;
    float acc[8][8];
#pragma unroll
    for (int i = 0; i < 8; ++i)
#pragma unroll
        for (int j = 0; j < 8; ++j) acc[i][j] = 0.f;
    for (int k4 = 0; k4 < 16; ++k4) {
        float xs[8][4];
#pragma unroll
        for (int i = 0; i < 8; ++i) {
            const float4 v = *(const float4*)&gS[(ty + 16 * i) * 68 + k4 * 4];
            xs[i][0] = v.x; xs[i][1] = v.y; xs[i][2] = v.z; xs[i][3] = v.w;
        }
#pragma unroll
        for (int kk = 0; kk < 4; ++kk) {
            const float4 w0 = *(const float4*)(wT + (k4 * 4 + kk) * 128 + c0);
            const float4 w1 = *(const float4*)(wT + (k4 * 4 + kk) * 128 + c0 + 4);
#pragma unroll
            for (int i = 0; i < 8; ++i) {
                const float xv = xs[i][kk];
                acc[i][0] += xv * w0.x; acc[i][1] += xv * w0.y;
                acc[i][2] += xv * w0.z; acc[i][3] += xv * w0.w;
                acc[i][4] += xv * w1.x; acc[i][5] += xv * w1.y;
                acc[i][6] += xv * w1.z; acc[i][7] += xv * w1.w;
            }
        }
    }
    const float* bi = dir ? bihb : bihf;
    const float* bh = dir ? bhhb : bhhf;
    float bsum[8];
    {
        const float4 b0 = *(const float4*)(bi + c0), b1 = *(const float4*)(bi + c0 + 4);
        const float4 h0 = *(const float4*)(bh + c0), h1 = *(const float4*)(bh + c0 + 4);
        bsum[0] = b0.x + h0.x; bsum[1] = b0.y + h0.y; bsum[2] = b0.z + h0.z; bsum[3] = b0.w + h0.w;
        bsum[4] = b1.x + h1.x; bsum[5] = b1.y + h1.y; bsum[6] = b1.z + h1.z; bsum[7] = b1.w + h1.w;
    }
    float* __restrict__ zrow = zx + (size_t)dir * 16777216 + (size_t)mt2 * 16384;
#pragma unroll
    for (int i = 0; i < 8; ++i) {
        const int r = ty + 16 * i;
        float4 o0, o1;
        o0.x = acc[i][0] + bsum[0]; o0.y = acc[i][1] + bsum[1];
        o0.z = acc[i][2] + bsum[2]; o0.w = acc[i][3] + bsum[3];
        o1.x = acc[i][4] + bsum[4]; o1.y = acc[i][5] + bsum[5];
        o1.z = acc[i][6] + bsum[6]; o1.w = acc[i][7] + bsum[7];
        *(float4*)&zrow[r * 128 + c0] = o0;
        *(float4*)&zrow[r * 128 + c0 + 4] = o1;
    }
}

// ---------------------------------------------------------------- single-wave recurrent LSTM
__device__ __forceinline__ float rl(float v, int l) {
    return __int_as_float(__builtin_amdgcn_readlane(__float_as_int(v), l));
}

// Best measured variant (R6/R10/R12: 131-133us). R7-R11 established ~132us as
// the compiler's register-policy floor for this shape. Do not re-litigate.
__global__ __launch_bounds__(64, 1) void k_lstm2(const float* __restrict__ zx,
                                                 float* __restrict__ hbuf,
                                                 const float* __restrict__ Whhf,
                                                 const float* __restrict__ Whhb) {
    const int n = blockIdx.x, dir = blockIdx.y, r = threadIdx.x;
    const bool lo = (r < 32);
    const float* __restrict__ Whh = dir ? Whhb : Whhf;
    const float4* W4 = (const float4*)Whh;
    const float4 wa0 = W4[r * 8 + 0], wa1 = W4[r * 8 + 1], wa2 = W4[r * 8 + 2], wa3 = W4[r * 8 + 3];
    const float4 wa4 = W4[r * 8 + 4], wa5 = W4[r * 8 + 5], wa6 = W4[r * 8 + 6], wa7 = W4[r * 8 + 7];
    const float4 wb0 = W4[(r + 64) * 8 + 0], wb1 = W4[(r + 64) * 8 + 1];
    const float4 wb2 = W4[(r + 64) * 8 + 2], wb3 = W4[(r + 64) * 8 + 3];
    const float4 wb4 = W4[(r + 64) * 8 + 4], wb5 = W4[(r + 64) * 8 + 5];
    const float4 wb6 = W4[(r + 64) * 8 + 6], wb7 = W4[(r + 64) * 8 + 7];
    const float* __restrict__ zxp = zx + (size_t)dir * 16777216 + (size_t)n * 16384;
    float* __restrict__ hout = hbuf + (size_t)n * 8192 + dir * 32 + r;
    float hv = 0.f, cv = 0.f;

#define SADDR(S_) (zxp + (size_t)(dir ? 127 - (S_) : (S_)) * 128)
#define DOT4(Q) {                                                           \
        const float h0 = rl(hv, 4 * Q + 0), h1 = rl(hv, 4 * Q + 1);         \
        const float h2 = rl(hv, 4 * Q + 2), h3 = rl(hv, 4 * Q + 3);         \
        a0 += h0 * wa##Q.x; b0 += h0 * wb##Q.x;                             \
        a1 += h1 * wa##Q.y; b1 += h1 * wb##Q.y;                             \
        a0 += h2 * wa##Q.z; b0 += h2 * wb##Q.z;                             \
        a1 += h3 * wa##Q.w; b1 += h3 * wb##Q.w;                             \
    }
#define STEP(S_, ZA, ZB) {                                                  \
        float a0 = (ZA), a1 = 0.f, b0 = (ZB), b1 = 0.f;                     \
        DOT4(0) DOT4(1) DOT4(2) DOT4(3) DOT4(4) DOT4(5) DOT4(6) DOT4(7)    \
        const float zi = a0 + a1, zg = b0 + b1;                             \
        const float eA = __expf(-zi);                                       \
        const float sA = 1.f / (1.f + eA);                                  \
        const float eB = __expf(lo ? -2.f * zg : -zg);                      \
        const float vB = lo ? (2.f / (1.f + eB) - 1.f) : (1.f / (1.f + eB));\
        const float fv = __shfl_xor(sA, 32);                                \
        const float ox = __shfl_xor(vB, 32);                                \
        cv = fv * cv + sA * vB;                                             \
        const float eC = __expf(-2.f * cv);                                 \
        const float tc = 2.f / (1.f + eC) - 1.f;                            \
        hv = ox * tc;                                                       \
        const int s__ = dir ? 127 - (S_) : (S_);                            \
        if (lo) hout[s__ * 64] = hv;                                        \
    }

    const float* p0 = SADDR(0);
    const float* p1 = SADDR(1);
    float zA0 = p0[r], zB0 = p0[r + 64];
    float zA1 = p1[r], zB1 = p1[r + 64];
    for (int s2 = 0; s2 < 64; ++s2) {
        int sp = 2 * s2 + 2; if (sp > 126) sp = 126;
        const float* pn0 = SADDR(sp);
        const float* pn1 = SADDR(sp + 1);
        const float nA0 = pn0[r], nB0 = pn0[r + 64];
        const float nA1 = pn1[r], nB1 = pn1[r + 64];
        STEP(2 * s2, zA0, zB0);
        STEP(2 * s2 + 1, zA1, zB1);
        zA0 = nA0; zB0 = nB0; zA1 = nA1; zB1 = nB1;
    }
#undef STEP
#undef DOT4
#undef SADDR
}

// ---------------------------------------------------------------- temporal attention per n
__global__ __launch_bounds__(256) void k_ta(float* __restrict__ ws,
                                            const float* __restrict__ tab,
                                            const float* __restrict__ tav) {
    __shared__ __align__(16) float hL[128 * 68];
    __shared__ float scL[128];
    __shared__ float sRed[4];
    __shared__ float sPart[256];
    const int n = blockIdx.x, tid = threadIdx.x, lane = tid & 63, wave = tid >> 6;
    const float4* __restrict__ hsrc4 = (const float4*)(ws + OFF_H + (size_t)n * 8192);
    for (int i4 = tid; i4 < 2048; i4 += 256) {
        const int row = i4 >> 4, c4 = i4 & 15;
        *(float4*)&hL[row * 68 + c4 * 4] = hsrc4[i4];
    }
    __syncthreads();
    const int ty8 = lane >> 3, ux = lane & 7;
    const int t0 = wave * 32 + ty8, u0 = ux * 8;
    const float* __restrict__ twt = ws + OFF_TAWT;
    float tb[8], tv[8];
    *(float4*)&tb[0] = *(const float4*)(tab + u0);
    *(float4*)&tb[4] = *(const float4*)(tab + u0 + 4);
    *(float4*)&tv[0] = *(const float4*)(tav + u0);
    *(float4*)&tv[4] = *(const float4*)(tav + u0 + 4);
    float a[4][8];
#pragma unroll
    for (int i = 0; i < 4; ++i)
#pragma unroll
        for (int j = 0; j < 8; ++j) a[i][j] = 0.f;
    for (int v4 = 0; v4 < 16; ++v4) {
        float xs[4][4];
#pragma unroll
        for (int i = 0; i < 4; ++i) {
            const float4 v = *(const float4*)&hL[(t0 + 8 * i) * 68 + v4 * 4];
            xs[i][0] = v.x; xs[i][1] = v.y; xs[i][2] = v.z; xs[i][3] = v.w;
        }
#pragma unroll
        for (int kk = 0; kk < 4; ++kk) {
            const float4 w0 = *(const float4*)(twt + (v4 * 4 + kk) * 64 + u0);
            const float4 w1 = *(const float4*)(twt + (v4 * 4 + kk) * 64 + u0 + 4);
#pragma unroll
            for (int i = 0; i < 4; ++i) {
                const float xv = xs[i][kk];
                a[i][0] += xv * w0.x; a[i][1] += xv * w0.y;
                a[i][2] += xv * w0.z; a[i][3] += xv * w0.w;
                a[i][4] += xv * w1.x; a[i][5] += xv * w1.y;
                a[i][6] += xv * w1.z; a[i][7] += xv * w1.w;
            }
        }
    }
#pragma unroll
    for (int i = 0; i < 4; ++i) {
        float s = 0.f;
#pragma unroll
        for (int u = 0; u < 8; ++u) s += tanhf(a[i][u] + tb[u]) * tv[u];
        s += __shfl_xor(s, 1); s += __shfl_xor(s, 2); s += __shfl_xor(s, 4);
        if (ux == 0) scL[t0 + 8 * i] = s;
    }
    __syncthreads();
    const float v = (tid < 128) ? scL[tid] : -1e30f;
    float mw = v;
    mw = fmaxf(mw, __shfl_xor(mw, 1)); mw = fmaxf(mw, __shfl_xor(mw, 2));
    mw = fmaxf(mw, __shfl_xor(mw, 4)); mw = fmaxf(mw, __shfl_xor(mw, 8));
    mw = fmaxf(mw, __shfl_xor(mw, 16)); mw = fmaxf(mw, __shfl_xor(mw, 32));
    if (lane == 0) sRed[wave] = mw;
    __syncthreads();
    const float m = fmaxf(fmaxf(sRed[0], sRed[1]), fmaxf(sRed[2], sRed[3]));
    const float p = (tid < 128) ? __expf((v - m) * INV_TEMP) : 0.f;
    float sw = p;
    sw += __shfl_xor(sw, 1); sw += __shfl_xor(sw, 2); sw += __shfl_xor(sw, 4);
    sw += __shfl_xor(sw, 8); sw += __shfl_xor(sw, 16); sw += __shfl_xor(sw, 32);
    __syncthreads();
    if (lane == 0) sRed[wave] = sw;
    __syncthreads();
    const float stot = sRed[0] + sRed[1] + sRed[2] + sRed[3];
    if (tid < 128) scL[tid] = p / stot;
    __syncthreads();
    float part = 0.f;
    for (int tt = 0; tt < 32; ++tt) {
        const int t = wave * 32 + tt;
        part += scL[t] * hL[t * 68 + lane];
    }
    sPart[wave * 64 + lane] = part;
    __syncthreads();
    if (tid < 64)
        ws[OFF_HP + (size_t)n * 64 + tid] =
            sPart[tid] + sPart[64 + tid] + sPart[128 + tid] + sPart[192 + tid];
}

// ---------------------------------------------------------------- channel attn + LN + MLP per b
__global__ __launch_bounds__(64) void k_final(const float* __restrict__ ws,
                                              const float* __restrict__ cpW, const float* __restrict__ cpb,
                                              const float* __restrict__ ng, const float* __restrict__ nb,
                                              const float* __restrict__ f1W, const float* __restrict__ f1b,
                                              const float* __restrict__ f2W, const float* __restrict__ f2b,
                                              float* __restrict__ out) {
    __shared__ float xc[64 * 65];
    __shared__ float wL[64];
    __shared__ float plL[64];
    __shared__ float h1L[32];
    const int b = blockIdx.x, tid = threadIdx.x;
    const float* hp = ws + OFF_HP + (size_t)b * 4096;
    for (int m = 0; m < 64; ++m) xc[m * 65 + tid] = hp[m * 64 + tid];
    __syncthreads();
    float s = cpb[0];
    for (int j = 0; j < 64; ++j) s += xc[tid * 65 + j] * cpW[j];
    float mm = s;
    for (int o = 1; o < 64; o <<= 1) mm = fmaxf(mm, __shfl_xor(mm, o));
    const float p = __expf(s - mm);
    float sum = p;
    for (int o = 1; o < 64; o <<= 1) sum += __shfl_xor(sum, o);
    wL[tid] = p / sum;
    __syncthreads();
    float pool = 0.f;
    for (int c = 0; c < 64; ++c) pool += xc[c * 65 + tid] * wL[c];
    float ms = pool;
    for (int o = 1; o < 64; o <<= 1) ms += __shfl_xor(ms, o);
    const float mean = ms * (1.f / 64.f);
    const float d = pool - mean;
    float vv = d * d;
    for (int o = 1; o < 64; o <<= 1) vv += __shfl_xor(vv, o);
    const float pl = d * rsqrtf(vv * (1.f / 64.f) + 1e-5f) * ng[tid] + nb[tid];
    plL[tid] = pl;
    __syncthreads();
    if (tid < 32) {
        float h1 = f1b[tid];
        for (int j = 0; j < 64; ++j) h1 += plL[j] * f1W[tid * 64 + j];
        h1L[tid] = fmaxf(h1, 0.f);
    }
    __syncthreads();
    if (tid < 3) {
        float o = f2b[tid];
        for (int uu = 0; uu < 32; ++uu) o += h1L[uu] * f2W[tid * 32 + uu];
        out[b * 3 + tid] = o;
    }
}

// ---------------------------------------------------------------- launch
extern "C" void kernel_launch(void* const* d_in, const int* in_sizes, int n_in,
                              void* d_out, int out_size, void* d_ws, size_t ws_size,
                              hipStream_t stream) {
    (void)in_sizes; (void)n_in; (void)out_size; (void)ws_size;
    const float* x      = (const float*)d_in[0];
    const float* spec_w = (const float*)d_in[1];
    const float* gat_W  = (const float*)d_in[2];
    const float* gat_a  = (const float*)d_in[3];
    const float* gat_ng = (const float*)d_in[4];
    const float* gat_nb = (const float*)d_in[5];
    const float* gat_rW = (const float*)d_in[6];
    const float* gat_rb = (const float*)d_in[7];
    const float* Wihf   = (const float*)d_in[8];
    const float* Whhf   = (const float*)d_in[9];
    const float* bihf   = (const float*)d_in[10];
    const float* bhhf   = (const float*)d_in[11];
    const float* Wihb   = (const float*)d_in[12];
    const float* Whhb   = (const float*)d_in[13];
    const float* bihb   = (const float*)d_in[14];
    const float* bhhb   = (const float*)d_in[15];
    const float* ta_W   = (const float*)d_in[16];
    const float* ta_b   = (const float*)d_in[17];
    const float* ta_v   = (const float*)d_in[18];
    const float* cp_W   = (const float*)d_in[19];
    const float* cp_b   = (const float*)d_in[20];
    const float* norm_g = (const float*)d_in[21];
    const float* norm_b = (const float*)d_in[22];
    const float* fc1_W  = (const float*)d_in[23];
    const float* fc1_b  = (const float*)d_in[24];
    const float* fc2_W  = (const float*)d_in[25];
    const float* fc2_b  = (const float*)d_in[26];
    float* ws  = (float*)d_ws;
    float* out = (float*)d_out;

    hipLaunchKernelGGL(k_prep, dim3(144), dim3(256), 0, stream, gat_W, gat_rW, ta_W, Wihf, Wihb, ws);
    hipLaunchKernelGGL(k_corr, dim3(64, 16), dim3(256), 0, stream, x, spec_w, ws);
    hipLaunchKernelGGL(k_reduceA, dim3(256), dim3(256), 0, stream, ws);
    hipLaunchKernelGGL(k_sparsify, dim3(16), dim3(64), 0, stream, ws);
    hipLaunchKernelGGL(k_wh, dim3(2048), dim3(256), 0, stream,
                       x, spec_w, ws + OFF_WTT, ws + OFF_RTT,
                       ws + OFF_WHS, ws + OFF_RS, gat_rb);
    hipLaunchKernelGGL(k_att, dim3(128, 16), dim3(256), 0, stream,
                       ws, ws + OFF_WHS, ws + OFF_RS, ws + OFF_G,
                       gat_a, gat_ng, gat_nb);
    hipLaunchKernelGGL(k_zx, dim3(1024, 2), dim3(256), 0, stream,
                       ws + OFF_G, ws, ws + OFF_ZX, bihf, bhhf, bihb, bhhb);
    hipLaunchKernelGGL(k_lstm2, dim3(1024, 2), dim3(64), 0, stream,
                       ws + OFF_ZX, ws + OFF_H, Whhf, Whhb);
    hipLaunchKernelGGL(k_ta, dim3(1024), dim3(256), 0, stream, ws, ta_b, ta_v);
    hipLaunchKernelGGL(k_final, dim3(16), dim3(64), 0, stream, ws, cp_W, cp_b,
                       norm_g, norm_b, fc1_W, fc1_b, fc2_W, fc2_b, out);
}

// Round 15
// 390.227 us; speedup vs baseline: 1.1717x; 1.0609x over previous
//
#include <hip/hip_runtime.h>
#include <math.h>

// ---- model sizes ----
#define BB 16
#define TT 128
#define CC 64
#define FF 128
// H=4, FO=16, H*FO=64, HID=32

static constexpr float INV_TEMP = 1.0f / 1.5f;

// ---- workspace offsets (in floats) ----
static constexpr size_t OFF_WTT   = 8192;       //  8192  WT[k][g]  (gat_W transposed)
static constexpr size_t OFF_RTT   = 16384;      //  8192  RT[k][g]  (gat_res_W transposed)
static constexpr size_t OFF_TAWT  = 24576;      //  4096  taWT[v][u]
static constexpr size_t OFF_AN    = 28672;      // 65536  An[b][i][j] row-major
static constexpr size_t OFF_A     = 94208;      // 65536  A[b][c][d]
static constexpr size_t OFF_G     = 1208320;    // 8388608 GAT output [b][t][c][64]
static constexpr size_t OFF_H     = 9596928;    // 8388608 BiLSTM out [n][tau][64]
static constexpr size_t OFF_HP    = 17985536;   // 65536  pooled [n][64]
static constexpr size_t OFF_WIHT  = 18051072;   // 16384  WihT[dir][64k][128g]
static constexpr size_t OFF_ZX    = 18067456;   // 33554432 zx[dir][n*128+t][128]
// aliases inside ZX region (all dead before k_zx runs):
static constexpr size_t OFF_WHS   = OFF_ZX + 16777216;  //  8388608: Wh [bt][64][64]
static constexpr size_t OFF_RS    = OFF_ZX + 25165824;  //  8388608: res+bias [bt][64][64]
// APART (corr partials) aliases the WHS region: alive only corr -> reduceA.
static constexpr size_t OFF_APART = OFF_WHS;            //  4194304 floats used

// ---------------------------------------------------------------- prep: weight transposes
__global__ __launch_bounds__(256) void k_prep(const float* __restrict__ gat_W,
                                              const float* __restrict__ gat_rW,
                                              const float* __restrict__ ta_W,
                                              const float* __restrict__ Wihf,
                                              const float* __restrict__ Wihb,
                                              float* __restrict__ ws) {
    int i = blockIdx.x * 256 + threadIdx.x;  // < 36864, grid 144
    if (i < 8192) {
        int k = i >> 6, g = i & 63;
        ws[OFF_WTT + i] = gat_W[g * 128 + k];
    } else if (i < 16384) {
        int j = i - 8192; int k = j >> 6, g = j & 63;
        ws[OFF_RTT + j] = gat_rW[g * 128 + k];
    } else if (i < 20480) {
        int j = i - 16384; int v = j >> 6, u = j & 63;
        ws[OFF_TAWT + j] = ta_W[u * 64 + v];
    } else if (i < 36864) {
        int j = i - 20480;  // WihT[dir][k][g] = Wih_dir[g][k]
        int dir = j >> 13, rem = j & 8191, k = rem >> 7, gg = rem & 127;
        const float* W = dir ? Wihb : Wihf;
        ws[OFF_WIHT + j] = W[gg * 64 + k];
    }
}

__device__ __forceinline__ float4 sigmul4(const float4 xv, const float4 wv) {
    float4 o;
    o.x = xv.x / (1.f + __expf(-wv.x));
    o.y = xv.y / (1.f + __expf(-wv.y));
    o.z = xv.z / (1.f + __expf(-wv.z));
    o.w = xv.w / (1.f + __expf(-wv.w));
    return o;
}

// ---------------------------------------------------------------- corr partial grams
__global__ __launch_bounds__(256) void k_corr(const float* __restrict__ x,
                                              const float* __restrict__ spec_w,
                                              float* __restrict__ ws) {
    __shared__ __align__(16) float tile[64 * 132];
    __shared__ float rn[64];
    const int ch = blockIdx.x, b = blockIdx.y, tid = threadIdx.x;
    const int lane = tid & 63, wave = tid >> 6;
    const int c0 = wave * 16 + ((lane >> 4) << 2);
    const int d0 = (lane & 15) << 2;
    const float4* __restrict__ sg4 = (const float4*)spec_w;
    float acc[4][4];
#pragma unroll
    for (int a = 0; a < 4; ++a)
#pragma unroll
        for (int e = 0; e < 4; ++e) acc[a][e] = 0.f;

    for (int t8 = 0; t8 < 2; ++t8) {
        const int t = ch * 2 + t8;
        __syncthreads();
        const float4* __restrict__ xp4 = (const float4*)(x + ((size_t)(b * TT + t)) * CC * FF);
        for (int i4 = tid; i4 < 2048; i4 += 256) {
            const int row = i4 >> 5, col4 = i4 & 31;
            *(float4*)&tile[row * 132 + col4 * 4] = sigmul4(xp4[i4], sg4[i4]);
        }
        __syncthreads();
        {   // row norms: 4 threads per row
            const int row = tid >> 2, part = tid & 3;
            const float4* tr = (const float4*)(tile + row * 132 + part * 32);
            float s = 0.f;
#pragma unroll
            for (int q = 0; q < 8; ++q) {
                const float4 v = tr[q];
                s += v.x * v.x + v.y * v.y + v.z * v.z + v.w * v.w;
            }
            s += __shfl_xor(s, 1); s += __shfl_xor(s, 2);
            if (part == 0) rn[row] = 1.f / (sqrtf(s) + 1e-8f);
        }
        __syncthreads();
        float dot[4][4];
#pragma unroll
        for (int a = 0; a < 4; ++a)
#pragma unroll
            for (int e = 0; e < 4; ++e) dot[a][e] = 0.f;
        for (int f4 = 0; f4 < 32; ++f4) {
            float4 xc4[4], xd4[4];
#pragma unroll
            for (int a = 0; a < 4; ++a) xc4[a] = *(const float4*)&tile[(c0 + a) * 132 + f4 * 4];
#pragma unroll
            for (int e = 0; e < 4; ++e) xd4[e] = *(const float4*)&tile[(d0 + e) * 132 + f4 * 4];
#pragma unroll
            for (int a = 0; a < 4; ++a)
#pragma unroll
                for (int e = 0; e < 4; ++e)
                    dot[a][e] += xc4[a].x * xd4[e].x + xc4[a].y * xd4[e].y +
                                 xc4[a].z * xd4[e].z + xc4[a].w * xd4[e].w;
        }
#pragma unroll
        for (int a = 0; a < 4; ++a) {
            const float ra = rn[c0 + a];
#pragma unroll
            for (int e = 0; e < 4; ++e) acc[a][e] += ra * rn[d0 + e] * dot[a][e];
        }
    }
    float* __restrict__ Ap = ws + OFF_APART + ((size_t)(b * 64 + ch)) * 4096;
#pragma unroll
    for (int a = 0; a < 4; ++a)
#pragma unroll
        for (int e = 0; e < 4; ++e) Ap[(c0 + a) * 64 + d0 + e] = acc[a][e];
}

// ---------------------------------------------------------------- reduce A (deterministic)
__global__ __launch_bounds__(256) void k_reduceA(float* __restrict__ ws) {
    int i = blockIdx.x * 256 + threadIdx.x;  // < 65536
    int b = i >> 12, e = i & 4095;
    const float* Ap = ws + OFF_APART + (size_t)b * 64 * 4096;
    float s = 0.f;
#pragma unroll 8
    for (int ch = 0; ch < 64; ++ch) s += Ap[ch * 4096 + e];
    ws[OFF_A + i] = s * (1.f / 128.f);
}

// ---------------------------------------------------------------- top-k sparsify -> An[i][j]
__global__ __launch_bounds__(64) void k_sparsify(float* __restrict__ ws) {
    __shared__ float As[64 * 65];
    __shared__ unsigned char kp[64 * 64];
    const int b = blockIdx.x, tid = threadIdx.x;  // 64 threads
    const float* Ag = ws + OFF_A + (size_t)b * 4096;
    for (int m = 0; m < 64; ++m) As[m * 65 + tid] = Ag[m * 64 + tid];
    __syncthreads();
    const int c = tid;
    int s0 = -1, s1 = -1, s2 = -1;
    for (int p = 0; p < 3; ++p) {
        float best = -1e30f; int bi = -1;
        for (int d = 0; d < 64; ++d) {
            if (d == s0 || d == s1) continue;
            float v = As[c * 65 + d];
            if (v > best) { best = v; bi = d; }
        }
        if (p == 0) s0 = bi; else if (p == 1) s1 = bi; else s2 = bi;
    }
    for (int d = 0; d < 64; ++d) {
        float v = As[c * 65 + d];
        kp[c * 64 + d] = (unsigned char)(((d == s0) | (d == s1) | (d == s2)) &&
                                         (v > 0.3f) && (d != c));
    }
    __syncthreads();
    float rs = 0.f;
    for (int d = 0; d < 64; ++d) {
        bool k2 = kp[c * 64 + d] || kp[d * 64 + c];
        rs += k2 ? As[c * 65 + d] : 0.f;
    }
    const float inv = 1.f / (rs + 1e-8f);
    float* An = ws + OFF_AN + (size_t)b * 4096;
    for (int d = 0; d < 64; ++d) {
        bool k2 = kp[c * 64 + d] || kp[d * 64 + c];
        An[c * 64 + d] = k2 ? As[c * 65 + d] * inv : 0.f;  // row-major [i][j]
    }
}

// ---------------------------------------------------------------- batched GEMM (8x4 tile, R11/R14-measured)
__global__ __launch_bounds__(256) void k_wh(const float* __restrict__ x,
                                            const float* __restrict__ spec_w,
                                            const float* __restrict__ wt,
                                            const float* __restrict__ rt,
                                            float* __restrict__ whs,
                                            float* __restrict__ rs,
                                            const float* __restrict__ res_b) {
    __shared__ __align__(16) float tile[64 * 132];
    const int bt = blockIdx.x, tid = threadIdx.x;
    const float4* __restrict__ xp4 = (const float4*)(x + (size_t)bt * 8192);
    const float4* __restrict__ sg4 = (const float4*)spec_w;
    for (int i4 = tid; i4 < 2048; i4 += 256) {
        const int row = i4 >> 5, col4 = i4 & 31;
        *(float4*)&tile[row * 132 + col4 * 4] = sigmul4(xp4[i4], sg4[i4]);
    }
    __syncthreads();
    const int tx = tid & 31, ty = tid >> 5;
    const int mat = tx >> 4, cx = tx & 15;
    const int r0 = ty * 8, c0 = cx * 4;
    const float* __restrict__ wbase = mat ? rt : wt;
    float acc[8][4];
#pragma unroll
    for (int i = 0; i < 8; ++i)
#pragma unroll
        for (int j = 0; j < 4; ++j) acc[i][j] = 0.f;
    for (int k4 = 0; k4 < 32; ++k4) {
        float xs[8][4];
#pragma unroll
        for (int i = 0; i < 8; ++i) {
            const float4 v = *(const float4*)&tile[(r0 + i) * 132 + k4 * 4];
            xs[i][0] = v.x; xs[i][1] = v.y; xs[i][2] = v.z; xs[i][3] = v.w;
        }
#pragma unroll
        for (int kk = 0; kk < 4; ++kk) {
            const float4 wv = *(const float4*)(wbase + (k4 * 4 + kk) * 64 + c0);
#pragma unroll
            for (int i = 0; i < 8; ++i) {
                acc[i][0] += xs[i][kk] * wv.x;
                acc[i][1] += xs[i][kk] * wv.y;
                acc[i][2] += xs[i][kk] * wv.z;
                acc[i][3] += xs[i][kk] * wv.w;
            }
        }
    }
    if (mat == 0) {
        float* __restrict__ op = whs + (size_t)bt * 4096;
#pragma unroll
        for (int i = 0; i < 8; ++i) {
            float4 o; o.x = acc[i][0]; o.y = acc[i][1]; o.z = acc[i][2]; o.w = acc[i][3];
            *(float4*)(op + (r0 + i) * 64 + c0) = o;
        }
    } else {
        const float4 rb = *(const float4*)(res_b + c0);
        float* __restrict__ op = rs + (size_t)bt * 4096;
#pragma unroll
        for (int i = 0; i < 8; ++i) {
            float4 o; o.x = acc[i][0] + rb.x; o.y = acc[i][1] + rb.y;
            o.z = acc[i][2] + rb.z; o.w = acc[i][3] + rb.w;
            *(float4*)(op + (r0 + i) * 64 + c0) = o;
        }
    }
}

// ---------------------------------------------------------------- attention per (b,t) (sWh LDS-staged)
__global__ __launch_bounds__(256) void k_att(const float* __restrict__ ws,
                                             const float* __restrict__ whs,
                                             const float* __restrict__ rs,
                                             float* __restrict__ g,
                                             const float* __restrict__ gat_a,
                                             const float* __restrict__ ln_g,
                                             const float* __restrict__ ln_b) {
    __shared__ __align__(16) float sWh[64 * 68];
    __shared__ float sAn[64 * 65];
    __shared__ float sEjT[256];   // [h][j]
    __shared__ float sStat[64 * 8];  // [i][0:4]=sum partials, [i][4:8]=sumsq
    const int t = blockIdx.x, b = blockIdx.y, tid = threadIdx.x;
    const size_t bt = (size_t)(b * TT + t);
    const float4* __restrict__ wh4 = (const float4*)(whs + bt * 4096);
    for (int i4 = tid; i4 < 1024; i4 += 256) {
        const int row = i4 >> 4, c4 = i4 & 15;
        *(float4*)&sWh[row * 68 + c4 * 4] = wh4[i4];
    }
    const float* __restrict__ ang = ws + OFF_AN + (size_t)b * 4096;
    for (int i = tid; i < 4096; i += 256) sAn[(i >> 6) * 65 + (i & 63)] = ang[i];
    __syncthreads();

    const int ia = tid & 63, ha = tid >> 6;
    float eiv = 0.f, ejv = 0.f;
    {
        const float* __restrict__ whrow = sWh + ia * 68 + ha * 16;
        const float* __restrict__ aip = gat_a + ha * 32;
#pragma unroll
        for (int q = 0; q < 16; ++q) {
            const float w = whrow[q];
            eiv += w * aip[q];
            ejv += w * aip[16 + q];
        }
    }
    sEjT[ha * 64 + ia] = ejv;
    __syncthreads();

    float ao[16];
#pragma unroll
    for (int f = 0; f < 16; ++f) ao[f] = 0.f;
    float sum = 0.f;
    const float* __restrict__ anrow = sAn + ia * 65;
    const float* __restrict__ ejrow = sEjT + ha * 64;
#pragma unroll 4
    for (int j = 0; j < 64; ++j) {
        const float s = eiv + ejrow[j];
        const float l = s > 0.f ? s : 0.2f * s;
        const float anv = anrow[j];
        const float z = (anv != 0.f || j == ia) ? (l + anv) : -1e9f;
        const float p = __expf(z * INV_TEMP);
        sum += p;
        const float* __restrict__ wj = sWh + j * 68 + ha * 16;
        const float4 w0 = *(const float4*)(wj);
        const float4 w1 = *(const float4*)(wj + 4);
        const float4 w2 = *(const float4*)(wj + 8);
        const float4 w3 = *(const float4*)(wj + 12);
        ao[0]  += p * w0.x; ao[1]  += p * w0.y; ao[2]  += p * w0.z; ao[3]  += p * w0.w;
        ao[4]  += p * w1.x; ao[5]  += p * w1.y; ao[6]  += p * w1.z; ao[7]  += p * w1.w;
        ao[8]  += p * w2.x; ao[9]  += p * w2.y; ao[10] += p * w2.z; ao[11] += p * w2.w;
        ao[12] += p * w3.x; ao[13] += p * w3.y; ao[14] += p * w3.z; ao[15] += p * w3.w;
    }
    const float inv = 1.f / sum;
    float val[16];
    float s1 = 0.f, s2 = 0.f;
    const float* __restrict__ rsp = rs + bt * 4096 + ia * 64 + ha * 16;
#pragma unroll
    for (int q = 0; q < 4; ++q) {
        const float4 rv = *(const float4*)(rsp + q * 4);
        val[q * 4 + 0] = ao[q * 4 + 0] * inv + rv.x;
        val[q * 4 + 1] = ao[q * 4 + 1] * inv + rv.y;
        val[q * 4 + 2] = ao[q * 4 + 2] * inv + rv.z;
        val[q * 4 + 3] = ao[q * 4 + 3] * inv + rv.w;
    }
#pragma unroll
    for (int f = 0; f < 16; ++f) { s1 += val[f]; s2 += val[f] * val[f]; }
    sStat[ia * 8 + ha] = s1;
    sStat[ia * 8 + 4 + ha] = s2;
    __syncthreads();
    const float tsum = sStat[ia * 8 + 0] + sStat[ia * 8 + 1] + sStat[ia * 8 + 2] + sStat[ia * 8 + 3];
    const float tsq  = sStat[ia * 8 + 4] + sStat[ia * 8 + 5] + sStat[ia * 8 + 6] + sStat[ia * 8 + 7];
    const float mean = tsum * (1.f / 64.f);
    const float var = tsq * (1.f / 64.f) - mean * mean;
    const float rstd = rsqrtf(var + 1e-5f);
    float* __restrict__ gout = g + bt * 4096 + ia * 64 + ha * 16;
#pragma unroll
    for (int q = 0; q < 4; ++q) {
        const float4 gm = *(const float4*)(ln_g + ha * 16 + q * 4);
        const float4 bt4 = *(const float4*)(ln_b + ha * 16 + q * 4);
        float4 o;
        o.x = fmaxf((val[q * 4 + 0] - mean) * rstd * gm.x + bt4.x, 0.f);
        o.y = fmaxf((val[q * 4 + 1] - mean) * rstd * gm.y + bt4.y, 0.f);
        o.z = fmaxf((val[q * 4 + 2] - mean) * rstd * gm.z + bt4.z, 0.f);
        o.w = fmaxf((val[q * 4 + 3] - mean) * rstd * gm.w + bt4.w, 0.f);
        *(float4*)(gout + q * 4) = o;
    }
}

// ---------------------------------------------------------------- zx GEMM: zx = g @ WihT + bias
__global__ __launch_bounds__(256) void k_zx(const float* __restrict__ gbuf,
                                            const float* __restrict__ ws,
                                            float* __restrict__ zx,
                                            const float* __restrict__ bihf, const float* __restrict__ bhhf,
                                            const float* __restrict__ bihb, const float* __restrict__ bhhb) {
    __shared__ __align__(16) float gS[128 * 68];
    const int mt2 = blockIdx.x, dir = blockIdx.y, tid = threadIdx.x;
    const float4* __restrict__ gsrc4 = (const float4*)(gbuf + (size_t)mt2 * 8192);
    for (int i4 = tid; i4 < 2048; i4 += 256) {
        const int row = i4 >> 4, c4 = i4 & 15;
        *(float4*)&gS[row * 68 + c4 * 4] = gsrc4[i4];
    }
    __syncthreads();
    const int ty = tid >> 4, cxx = tid & 15;
    const int c0 = cxx * 8;
    const float* __restrict__ wT = ws + OFF_WIHT + (size_t)dir * 8192;
    float acc[8][8];
#pragma unroll
    for (int i = 0; i < 8; ++i)
#pragma unroll
        for (int j = 0; j < 8; ++j) acc[i][j] = 0.f;
    for (int k4 = 0; k4 < 16; ++k4) {
        float xs[8][4];
#pragma unroll
        for (int i = 0; i < 8; ++i) {
            const float4 v = *(const float4*)&gS[(ty + 16 * i) * 68 + k4 * 4];
            xs[i][0] = v.x; xs[i][1] = v.y; xs[i][2] = v.z; xs[i][3] = v.w;
        }
#pragma unroll
        for (int kk = 0; kk < 4; ++kk) {
            const float4 w0 = *(const float4*)(wT + (k4 * 4 + kk) * 128 + c0);
            const float4 w1 = *(const float4*)(wT + (k4 * 4 + kk) * 128 + c0 + 4);
#pragma unroll
            for (int i = 0; i < 8; ++i) {
                const float xv = xs[i][kk];
                acc[i][0] += xv * w0.x; acc[i][1] += xv * w0.y;
                acc[i][2] += xv * w0.z; acc[i][3] += xv * w0.w;
                acc[i][4] += xv * w1.x; acc[i][5] += xv * w1.y;
                acc[i][6] += xv * w1.z; acc[i][7] += xv * w1.w;
            }
        }
    }
    const float* bi = dir ? bihb : bihf;
    const float* bh = dir ? bhhb : bhhf;
    float bsum[8];
    {
        const float4 b0 = *(const float4*)(bi + c0), b1 = *(const float4*)(bi + c0 + 4);
        const float4 h0 = *(const float4*)(bh + c0), h1 = *(const float4*)(bh + c0 + 4);
        bsum[0] = b0.x + h0.x; bsum[1] = b0.y + h0.y; bsum[2] = b0.z + h0.z; bsum[3] = b0.w + h0.w;
        bsum[4] = b1.x + h1.x; bsum[5] = b1.y + h1.y; bsum[6] = b1.z + h1.z; bsum[7] = b1.w + h1.w;
    }
    float* __restrict__ zrow = zx + (size_t)dir * 16777216 + (size_t)mt2 * 16384;
#pragma unroll
    for (int i = 0; i < 8; ++i) {
        const int r = ty + 16 * i;
        float4 o0, o1;
        o0.x = acc[i][0] + bsum[0]; o0.y = acc[i][1] + bsum[1];
        o0.z = acc[i][2] + bsum[2]; o0.w = acc[i][3] + bsum[3];
        o1.x = acc[i][4] + bsum[4]; o1.y = acc[i][5] + bsum[5];
        o1.z = acc[i][6] + bsum[6]; o1.w = acc[i][7] + bsum[7];
        *(float4*)&zrow[r * 128 + c0] = o0;
        *(float4*)&zrow[r * 128 + c0 + 4] = o1;
    }
}

// ---------------------------------------------------------------- single-wave recurrent LSTM
__device__ __forceinline__ float rl(float v, int l) {
    return __int_as_float(__builtin_amdgcn_readlane(__float_as_int(v), l));
}

// R14 analysis: lstm2's 132us = spill working set 2048 waves x 256B = 33MB
// scratch > 32MB L2 -> per-step reloads thrash HBM. k_lstm6 puts BOTH weight
// halves in LDS (18KB: row j at float4 slot j*9+q; 9==1 mod 8 so word-bank =
// 4*((j+q)%8) -> each lane-octet covers all 8 bank-quads per q, conflict-free).
// Zero register-array ask -> nothing to spill; 16 ds_read_b128/step interleaved
// with the FMA chain. Base indices pinned per step so loads can't be
// hoisted-then-spilled. Math order identical to lstm2 (bit-identical output).
__global__ __launch_bounds__(64, 1) void k_lstm6(const float* __restrict__ zx,
                                                 float* __restrict__ hbuf,
                                                 const float* __restrict__ Whhf,
                                                 const float* __restrict__ Whhb) {
    __shared__ __align__(16) float swb[128 * 36];  // 18 KB
    const int n = blockIdx.x, dir = blockIdx.y, r = threadIdx.x;
    const bool lo = (r < 32);
    const float* __restrict__ Whh = dir ? Whhb : Whhf;
    const float4* W4 = (const float4*)Whh;
    {
        float4* sw = (float4*)swb;
#pragma unroll
        for (int m = 0; m < 16; ++m) {
            const int idx = r + 64 * m;          // 0..1023, coalesced
            const int j = idx >> 3, q = idx & 7;
            sw[j * 9 + q] = W4[idx];
        }
    }
    __syncthreads();
    const float4* sw4 = (const float4*)swb;
    int baseA = r * 9;            // row r      (wa)
    int baseB = (r + 64) * 9;     // row r+64   (wb)
    const float* __restrict__ zxp = zx + (size_t)dir * 16777216 + (size_t)n * 16384;
    float* __restrict__ hout = hbuf + (size_t)n * 8192 + dir * 32 + r;
    float hv = 0.f, cv = 0.f;

#define SADDR(S_) (zxp + (size_t)(dir ? 127 - (S_) : (S_)) * 128)
    // identical accumulation order to lstm2's DOT4: a0 even k, a1 odd k
#define DOTQL(Q) {                                                          \
        const float4 u = sw4[baseA + Q];                                    \
        const float4 v = sw4[baseB + Q];                                    \
        const float h0 = rl(hv, 4 * Q + 0), h1 = rl(hv, 4 * Q + 1);         \
        const float h2 = rl(hv, 4 * Q + 2), h3 = rl(hv, 4 * Q + 3);         \
        a0 += h0 * u.x; b0 += h0 * v.x;                                     \
        a1 += h1 * u.y; b1 += h1 * v.y;                                     \
        a0 += h2 * u.z; b0 += h2 * v.z;                                     \
        a1 += h3 * u.w; b1 += h3 * v.w;                                     \
    }
#define STEP(S_, ZA, ZB) {                                                  \
        asm volatile("" : "+v"(baseA), "+v"(baseB));                        \
        float a0 = (ZA), a1 = 0.f, b0 = (ZB), b1 = 0.f;                     \
        DOTQL(0) DOTQL(1) DOTQL(2) DOTQL(3)                                 \
        DOTQL(4) DOTQL(5) DOTQL(6) DOTQL(7)                                 \
        const float zi = a0 + a1, zg = b0 + b1;                             \
        const float eA = __expf(-zi);                                       \
        const float sA = 1.f / (1.f + eA);                                  \
        const float eB = __expf(lo ? -2.f * zg : -zg);                      \
        const float vB = lo ? (2.f / (1.f + eB) - 1.f) : (1.f / (1.f + eB));\
        const float fv = __shfl_xor(sA, 32);                                \
        const float ox = __shfl_xor(vB, 32);                                \
        cv = fv * cv + sA * vB;                                             \
        const float eC = __expf(-2.f * cv);                                 \
        const float tc = 2.f / (1.f + eC) - 1.f;                            \
        hv = ox * tc;                                                       \
        const int s__ = dir ? 127 - (S_) : (S_);                            \
        if (lo) hout[s__ * 64] = hv;                                        \
    }

    const float* p0 = SADDR(0);
    const float* p1 = SADDR(1);
    float zA0 = p0[r], zB0 = p0[r + 64];
    float zA1 = p1[r], zB1 = p1[r + 64];
    for (int s2 = 0; s2 < 64; ++s2) {
        int sp = 2 * s2 + 2; if (sp > 126) sp = 126;
        const float* pn0 = SADDR(sp);
        const float* pn1 = SADDR(sp + 1);
        const float nA0 = pn0[r], nB0 = pn0[r + 64];
        const float nA1 = pn1[r], nB1 = pn1[r + 64];
        STEP(2 * s2, zA0, zB0);
        STEP(2 * s2 + 1, zA1, zB1);
        zA0 = nA0; zB0 = nB0; zA1 = nA1; zB1 = nB1;
    }
#undef STEP
#undef DOTQL
#undef SADDR
}

// ---------------------------------------------------------------- temporal attention per n
__global__ __launch_bounds__(256) void k_ta(float* __restrict__ ws,
                                            const float* __restrict__ tab,
                                            const float* __restrict__ tav) {
    __shared__ __align__(16) float hL[128 * 68];
    __shared__ float scL[128];
    __shared__ float sRed[4];
    __shared__ float sPart[256];
    const int n = blockIdx.x, tid = threadIdx.x, lane = tid & 63, wave = tid >> 6;
    const float4* __restrict__ hsrc4 = (const float4*)(ws + OFF_H + (size_t)n * 8192);
    for (int i4 = tid; i4 < 2048; i4 += 256) {
        const int row = i4 >> 4, c4 = i4 & 15;
        *(float4*)&hL[row * 68 + c4 * 4] = hsrc4[i4];
    }
    __syncthreads();
    const int ty8 = lane >> 3, ux = lane & 7;
    const int t0 = wave * 32 + ty8, u0 = ux * 8;
    const float* __restrict__ twt = ws + OFF_TAWT;
    float tb[8], tv[8];
    *(float4*)&tb[0] = *(const float4*)(tab + u0);
    *(float4*)&tb[4] = *(const float4*)(tab + u0 + 4);
    *(float4*)&tv[0] = *(const float4*)(tav + u0);
    *(float4*)&tv[4] = *(const float4*)(tav + u0 + 4);
    float a[4][8];
#pragma unroll
    for (int i = 0; i < 4; ++i)
#pragma unroll
        for (int j = 0; j < 8; ++j) a[i][j] = 0.f;
    for (int v4 = 0; v4 < 16; ++v4) {
        float xs[4][4];
#pragma unroll
        for (int i = 0; i < 4; ++i) {
            const float4 v = *(const float4*)&hL[(t0 + 8 * i) * 68 + v4 * 4];
            xs[i][0] = v.x; xs[i][1] = v.y; xs[i][2] = v.z; xs[i][3] = v.w;
        }
#pragma unroll
        for (int kk = 0; kk < 4; ++kk) {
            const float4 w0 = *(const float4*)(twt + (v4 * 4 + kk) * 64 + u0);
            const float4 w1 = *(const float4*)(twt + (v4 * 4 + kk) * 64 + u0 + 4);
#pragma unroll
            for (int i = 0; i < 4; ++i) {
                const float xv = xs[i][kk];
                a[i][0] += xv * w0.x; a[i][1] += xv * w0.y;
                a[i][2] += xv * w0.z; a[i][3] += xv * w0.w;
                a[i][4] += xv * w1.x; a[i][5] += xv * w1.y;
                a[i][6] += xv * w1.z; a[i][7] += xv * w1.w;
            }
        }
    }
#pragma unroll
    for (int i = 0; i < 4; ++i) {
        float s = 0.f;
#pragma unroll
        for (int u = 0; u < 8; ++u) s += tanhf(a[i][u] + tb[u]) * tv[u];
        s += __shfl_xor(s, 1); s += __shfl_xor(s, 2); s += __shfl_xor(s, 4);
        if (ux == 0) scL[t0 + 8 * i] = s;
    }
    __syncthreads();
    const float v = (tid < 128) ? scL[tid] : -1e30f;
    float mw = v;
    mw = fmaxf(mw, __shfl_xor(mw, 1)); mw = fmaxf(mw, __shfl_xor(mw, 2));
    mw = fmaxf(mw, __shfl_xor(mw, 4)); mw = fmaxf(mw, __shfl_xor(mw, 8));
    mw = fmaxf(mw, __shfl_xor(mw, 16)); mw = fmaxf(mw, __shfl_xor(mw, 32));
    if (lane == 0) sRed[wave] = mw;
    __syncthreads();
    const float m = fmaxf(fmaxf(sRed[0], sRed[1]), fmaxf(sRed[2], sRed[3]));
    const float p = (tid < 128) ? __expf((v - m) * INV_TEMP) : 0.f;
    float sw = p;
    sw += __shfl_xor(sw, 1); sw += __shfl_xor(sw, 2); sw += __shfl_xor(sw, 4);
    sw += __shfl_xor(sw, 8); sw += __shfl_xor(sw, 16); sw += __shfl_xor(sw, 32);
    __syncthreads();
    if (lane == 0) sRed[wave] = sw;
    __syncthreads();
    const float stot = sRed[0] + sRed[1] + sRed[2] + sRed[3];
    if (tid < 128) scL[tid] = p / stot;
    __syncthreads();
    float part = 0.f;
    for (int tt = 0; tt < 32; ++tt) {
        const int t = wave * 32 + tt;
        part += scL[t] * hL[t * 68 + lane];
    }
    sPart[wave * 64 + lane] = part;
    __syncthreads();
    if (tid < 64)
        ws[OFF_HP + (size_t)n * 64 + tid] =
            sPart[tid] + sPart[64 + tid] + sPart[128 + tid] + sPart[192 + tid];
}

// ---------------------------------------------------------------- channel attn + LN + MLP per b
__global__ __launch_bounds__(64) void k_final(const float* __restrict__ ws,
                                              const float* __restrict__ cpW, const float* __restrict__ cpb,
                                              const float* __restrict__ ng, const float* __restrict__ nb,
                                              const float* __restrict__ f1W, const float* __restrict__ f1b,
                                              const float* __restrict__ f2W, const float* __restrict__ f2b,
                                              float* __restrict__ out) {
    __shared__ float xc[64 * 65];
    __shared__ float wL[64];
    __shared__ float plL[64];
    __shared__ float h1L[32];
    const int b = blockIdx.x, tid = threadIdx.x;
    const float* hp = ws + OFF_HP + (size_t)b * 4096;
    for (int m = 0; m < 64; ++m) xc[m * 65 + tid] = hp[m * 64 + tid];
    __syncthreads();
    float s = cpb[0];
    for (int j = 0; j < 64; ++j) s += xc[tid * 65 + j] * cpW[j];
    float mm = s;
    for (int o = 1; o < 64; o <<= 1) mm = fmaxf(mm, __shfl_xor(mm, o));
    const float p = __expf(s - mm);
    float sum = p;
    for (int o = 1; o < 64; o <<= 1) sum += __shfl_xor(sum, o);
    wL[tid] = p / sum;
    __syncthreads();
    float pool = 0.f;
    for (int c = 0; c < 64; ++c) pool += xc[c * 65 + tid] * wL[c];
    float ms = pool;
    for (int o = 1; o < 64; o <<= 1) ms += __shfl_xor(ms, o);
    const float mean = ms * (1.f / 64.f);
    const float d = pool - mean;
    float vv = d * d;
    for (int o = 1; o < 64; o <<= 1) vv += __shfl_xor(vv, o);
    const float pl = d * rsqrtf(vv * (1.f / 64.f) + 1e-5f) * ng[tid] + nb[tid];
    plL[tid] = pl;
    __syncthreads();
    if (tid < 32) {
        float h1 = f1b[tid];
        for (int j = 0; j < 64; ++j) h1 += plL[j] * f1W[tid * 64 + j];
        h1L[tid] = fmaxf(h1, 0.f);
    }
    __syncthreads();
    if (tid < 3) {
        float o = f2b[tid];
        for (int uu = 0; uu < 32; ++uu) o += h1L[uu] * f2W[tid * 32 + uu];
        out[b * 3 + tid] = o;
    }
}

// ---------------------------------------------------------------- launch
extern "C" void kernel_launch(void* const* d_in, const int* in_sizes, int n_in,
                              void* d_out, int out_size, void* d_ws, size_t ws_size,
                              hipStream_t stream) {
    (void)in_sizes; (void)n_in; (void)out_size; (void)ws_size;
    const float* x      = (const float*)d_in[0];
    const float* spec_w = (const float*)d_in[1];
    const float* gat_W  = (const float*)d_in[2];
    const float* gat_a  = (const float*)d_in[3];
    const float* gat_ng = (const float*)d_in[4];
    const float* gat_nb = (const float*)d_in[5];
    const float* gat_rW = (const float*)d_in[6];
    const float* gat_rb = (const float*)d_in[7];
    const float* Wihf   = (const float*)d_in[8];
    const float* Whhf   = (const float*)d_in[9];
    const float* bihf   = (const float*)d_in[10];
    const float* bhhf   = (const float*)d_in[11];
    const float* Wihb   = (const float*)d_in[12];
    const float* Whhb   = (const float*)d_in[13];
    const float* bihb   = (const float*)d_in[14];
    const float* bhhb   = (const float*)d_in[15];
    const float* ta_W   = (const float*)d_in[16];
    const float* ta_b   = (const float*)d_in[17];
    const float* ta_v   = (const float*)d_in[18];
    const float* cp_W   = (const float*)d_in[19];
    const float* cp_b   = (const float*)d_in[20];
    const float* norm_g = (const float*)d_in[21];
    const float* norm_b = (const float*)d_in[22];
    const float* fc1_W  = (const float*)d_in[23];
    const float* fc1_b  = (const float*)d_in[24];
    const float* fc2_W  = (const float*)d_in[25];
    const float* fc2_b  = (const float*)d_in[26];
    float* ws  = (float*)d_ws;
    float* out = (float*)d_out;

    hipLaunchKernelGGL(k_prep, dim3(144), dim3(256), 0, stream, gat_W, gat_rW, ta_W, Wihf, Wihb, ws);
    hipLaunchKernelGGL(k_corr, dim3(64, 16), dim3(256), 0, stream, x, spec_w, ws);
    hipLaunchKernelGGL(k_reduceA, dim3(256), dim3(256), 0, stream, ws);
    hipLaunchKernelGGL(k_sparsify, dim3(16), dim3(64), 0, stream, ws);
    hipLaunchKernelGGL(k_wh, dim3(2048), dim3(256), 0, stream,
                       x, spec_w, ws + OFF_WTT, ws + OFF_RTT,
                       ws + OFF_WHS, ws + OFF_RS, gat_rb);
    hipLaunchKernelGGL(k_att, dim3(128, 16), dim3(256), 0, stream,
                       ws, ws + OFF_WHS, ws + OFF_RS, ws + OFF_G,
                       gat_a, gat_ng, gat_nb);
    hipLaunchKernelGGL(k_zx, dim3(1024, 2), dim3(256), 0, stream,
                       ws + OFF_G, ws, ws + OFF_ZX, bihf, bhhf, bihb, bhhb);
    hipLaunchKernelGGL(k_lstm6, dim3(1024, 2), dim3(64), 0, stream,
                       ws + OFF_ZX, ws + OFF_H, Whhf, Whhb);
    hipLaunchKernelGGL(k_ta, dim3(1024), dim3(256), 0, stream, ws, ta_b, ta_v);
    hipLaunchKernelGGL(k_final, dim3(16), dim3(64), 0, stream, ws, cp_W, cp_b,
                       norm_g, norm_b, fc1_W, fc1_b, fc2_W, fc2_b, out);
}